// Round 1
// baseline (304.214 us; speedup 1.0000x reference)
//
#include <hip/hip_runtime.h>

typedef _Float16 f16;
typedef __attribute__((ext_vector_type(8))) _Float16 f16x8;
typedef __attribute__((ext_vector_type(4))) float f32x4;

#define D_MODEL 1024
#define SEQ 2048
#define NBATCH 4
#define NROWS (NBATCH * SEQ)  // 8192

// ---------------------------------------------------------------- utilities
__device__ __forceinline__ void gload16(const void* g, void* l) {
  __builtin_amdgcn_global_load_lds(
      (__attribute__((address_space(1))) void*)(void*)g,
      (__attribute__((address_space(3))) void*)l, 16, 0, 0);
}

// ------------------------------------------------------------- GEMM core
// C[128x128] = A[128xK] * BT[128xK]^T, A/BT row-major f16, fp32 accum.
// 256 threads (4 waves, 2x2 of 64x64), BK=32, mfma 16x16x32.
__device__ __forceinline__ void gemm_core(
    const f16* __restrict__ A, const f16* __restrict__ BT,
    int K, int lda, int ldb, f32x4 acc[4][4], f16* lds)
{
  f16* ldsA = lds;          // [128][32]
  f16* ldsB = lds + 4096;   // [128][32]
  const int t = threadIdx.x;
  const int lane = t & 63;
  const int w = t >> 6;
  const int wr = (w >> 1) * 64;
  const int wc = (w & 1) * 64;
  const int r  = t >> 2;          // staging row 0..63
  const int kc = (t & 3) * 8;     // staging k offset
  const f16* ga0 = A  + (size_t)r * lda + kc;
  const f16* ga1 = A  + (size_t)(r + 64) * lda + kc;
  const f16* gb0 = BT + (size_t)r * ldb + kc;
  const f16* gb1 = BT + (size_t)(r + 64) * ldb + kc;
  f16* la0 = ldsA + t * 8;
  f16* la1 = ldsA + 2048 + t * 8;
  f16* lb0 = ldsB + t * 8;
  f16* lb1 = ldsB + 2048 + t * 8;
  const int fr = lane & 15;
  const int kq = (lane >> 4) * 8;

  for (int k0 = 0; k0 < K; k0 += 32) {
    gload16(ga0 + k0, la0);
    gload16(ga1 + k0, la1);
    gload16(gb0 + k0, lb0);
    gload16(gb1 + k0, lb1);
    asm volatile("s_waitcnt vmcnt(0)" ::: "memory");
    __syncthreads();
    f16x8 af[4], bfr[4];
#pragma unroll
    for (int i = 0; i < 4; ++i) {
      af[i]  = *(const f16x8*)(ldsA + (wr + i * 16 + fr) * 32 + kq);
      bfr[i] = *(const f16x8*)(ldsB + (wc + i * 16 + fr) * 32 + kq);
    }
#pragma unroll
    for (int mi = 0; mi < 4; ++mi)
#pragma unroll
      for (int ni = 0; ni < 4; ++ni)
        acc[mi][ni] = __builtin_amdgcn_mfma_f32_16x16x32_f16(
            af[mi], bfr[ni], acc[mi][ni], 0, 0, 0);
    __syncthreads();
  }
}

// ------------------------------------------------- GEMM1: QKV + scramble
// z=0:Q z=1:K -> scrambled (B,S,D); z=2:V -> scrambled-transposed (B,D,S)
__global__ __launch_bounds__(256) void k_gemm_qkv(
    const f16* __restrict__ srch, const f16* __restrict__ wt,
    f16* __restrict__ qt, f16* __restrict__ kt, f16* __restrict__ vtT)
{
  __shared__ f16 lds[8192];
  const int z = blockIdx.z;
  const f16* A  = srch + (size_t)blockIdx.x * 128 * D_MODEL;
  const f16* BT = wt + ((size_t)z << 20) + (size_t)blockIdx.y * 128 * D_MODEL;
  f32x4 acc[4][4];
#pragma unroll
  for (int i = 0; i < 4; ++i)
#pragma unroll
    for (int j = 0; j < 4; ++j) acc[i][j] = f32x4{0.f, 0.f, 0.f, 0.f};
  gemm_core(A, BT, D_MODEL, D_MODEL, D_MODEL, acc, lds);

  const int t = threadIdx.x, lane = t & 63, w = t >> 6;
  const int wr = (w >> 1) * 64, wc = (w & 1) * 64;
  const int row0 = blockIdx.x * 128 + wr + (lane >> 4) * 4;
  const int col0 = blockIdx.y * 128 + wc + (lane & 15);
  f16* dst01 = (z == 0) ? qt : kt;
#pragma unroll
  for (int mi = 0; mi < 4; ++mi)
#pragma unroll
    for (int ni = 0; ni < 4; ++ni)
#pragma unroll
      for (int q = 0; q < 4; ++q) {
        const int sg = row0 + mi * 16 + q;         // global row in 0..8191
        const int j  = col0 + ni * 16;             // col in 0..1023
        const int b = sg >> 11, s = sg & 2047;
        const int sp = ((j >> 6) << 7) + (s >> 4); // scrambled row
        const int dp = ((s & 15) << 6) | (j & 63); // scrambled col
        const f16 val = (f16)acc[mi][ni][q];
        if (z < 2)
          dst01[((size_t)b << 21) + ((size_t)sp << 10) + dp] = val;
        else
          vtT[((size_t)b << 21) + ((size_t)dp << 11) + sp] = val;
      }
}

// ------------------------------------------- generic f32-output batched GEMM
__global__ __launch_bounds__(256) void k_gemm_f32(
    const f16* __restrict__ A, const f16* __restrict__ BT, float* __restrict__ C,
    int K, int lda, int ldb, int ldc, float scale,
    size_t sA, size_t sB, size_t sC)
{
  __shared__ f16 lds[8192];
  const f16* Ab = A + sA * blockIdx.z + (size_t)blockIdx.x * 128 * lda;
  const f16* Bb = BT + sB * blockIdx.z + (size_t)blockIdx.y * 128 * ldb;
  float* Cb = C + sC * blockIdx.z;
  f32x4 acc[4][4];
#pragma unroll
  for (int i = 0; i < 4; ++i)
#pragma unroll
    for (int j = 0; j < 4; ++j) acc[i][j] = f32x4{0.f, 0.f, 0.f, 0.f};
  gemm_core(Ab, Bb, K, lda, ldb, acc, lds);

  const int t = threadIdx.x, lane = t & 63, w = t >> 6;
  const int wr = (w >> 1) * 64, wc = (w & 1) * 64;
  const int row0 = blockIdx.x * 128 + wr + (lane >> 4) * 4;
  const int col0 = blockIdx.y * 128 + wc + (lane & 15);
#pragma unroll
  for (int mi = 0; mi < 4; ++mi)
#pragma unroll
    for (int ni = 0; ni < 4; ++ni)
#pragma unroll
      for (int q = 0; q < 4; ++q)
        Cb[(size_t)(row0 + mi * 16 + q) * ldc + col0 + ni * 16] =
            acc[mi][ni][q] * scale;
}

// -------------------------------------------------------------- casts
__global__ __launch_bounds__(256) void k_cast_f16(const float* __restrict__ in,
                                                  f16* __restrict__ out)
{
  const size_t i = (size_t)blockIdx.x * 256 + threadIdx.x;  // per 8 elements
  const float4* p = (const float4*)in;
  float4 v0 = p[2 * i], v1 = p[2 * i + 1];
  f16x8 o;
  o[0] = (f16)v0.x; o[1] = (f16)v0.y; o[2] = (f16)v0.z; o[3] = (f16)v0.w;
  o[4] = (f16)v1.x; o[5] = (f16)v1.y; o[6] = (f16)v1.z; o[7] = (f16)v1.w;
  *(f16x8*)(out + 8 * i) = o;
}

// transpose+cast 1024x1024 W (k,n) fp32 -> (n,k) f16; z selects matrix
__global__ __launch_bounds__(256) void k_castT(
    const float* __restrict__ w0, const float* __restrict__ w1,
    const float* __restrict__ w2, f16* __restrict__ out)
{
  const float* in = (blockIdx.z == 0) ? w0 : (blockIdx.z == 1 ? w1 : w2);
  f16* o = out + ((size_t)blockIdx.z << 20);
  __shared__ f16 tile[64][65];
  const int t = threadIdx.x;
  const int rr = t >> 4, c4 = (t & 15) * 4;
  const int r0 = blockIdx.x * 64, c0 = blockIdx.y * 64;
#pragma unroll
  for (int i = 0; i < 4; ++i) {
    float4 f = *(const float4*)(in + (size_t)(r0 + rr + 16 * i) * 1024 + c0 + c4);
    tile[rr + 16 * i][c4 + 0] = (f16)f.x;
    tile[rr + 16 * i][c4 + 1] = (f16)f.y;
    tile[rr + 16 * i][c4 + 2] = (f16)f.z;
    tile[rr + 16 * i][c4 + 3] = (f16)f.w;
  }
  __syncthreads();
#pragma unroll
  for (int i = 0; i < 4; ++i) {
    const int n = c0 + rr + 16 * i;
    f16* dst = o + (size_t)n * 1024 + r0 + c4;
    dst[0] = tile[c4 + 0][rr + 16 * i];
    dst[1] = tile[c4 + 1][rr + 16 * i];
    dst[2] = tile[c4 + 2][rr + 16 * i];
    dst[3] = tile[c4 + 3][rr + 16 * i];
  }
}

// ------------------------------------------------------- softmax (in place)
__global__ __launch_bounds__(256) void k_softmax(float* __restrict__ sc,
                                                 f16* __restrict__ abf)
{
  const size_t base = (size_t)blockIdx.x * 2048;
  const int t = threadIdx.x, lane = t & 63, w = t >> 6;
  float4* p = (float4*)(sc + base);
  float4 v0 = p[2 * t], v1 = p[2 * t + 1];
  float m = fmaxf(fmaxf(fmaxf(v0.x, v0.y), fmaxf(v0.z, v0.w)),
                  fmaxf(fmaxf(v1.x, v1.y), fmaxf(v1.z, v1.w)));
#pragma unroll
  for (int off = 1; off < 64; off <<= 1) m = fmaxf(m, __shfl_xor(m, off));
  __shared__ float red[8];
  if (lane == 0) red[w] = m;
  __syncthreads();
  m = fmaxf(fmaxf(red[0], red[1]), fmaxf(red[2], red[3]));
  v0.x = __expf(v0.x - m); v0.y = __expf(v0.y - m);
  v0.z = __expf(v0.z - m); v0.w = __expf(v0.w - m);
  v1.x = __expf(v1.x - m); v1.y = __expf(v1.y - m);
  v1.z = __expf(v1.z - m); v1.w = __expf(v1.w - m);
  float s = v0.x + v0.y + v0.z + v0.w + v1.x + v1.y + v1.z + v1.w;
#pragma unroll
  for (int off = 1; off < 64; off <<= 1) s += __shfl_xor(s, off);
  if (lane == 0) red[4 + w] = s;
  __syncthreads();
  s = red[4] + red[5] + red[6] + red[7];
  const float inv = 1.0f / s;
  v0.x *= inv; v0.y *= inv; v0.z *= inv; v0.w *= inv;
  v1.x *= inv; v1.y *= inv; v1.z *= inv; v1.w *= inv;
  p[2 * t] = v0; p[2 * t + 1] = v1;
  f16x8 o;
  o[0] = (f16)v0.x; o[1] = (f16)v0.y; o[2] = (f16)v0.z; o[3] = (f16)v0.w;
  o[4] = (f16)v1.x; o[5] = (f16)v1.y; o[6] = (f16)v1.z; o[7] = (f16)v1.w;
  *(f16x8*)(abf + base + (size_t)t * 8) = o;
}

// --------------------------------------------- fused LN1 + add + LN2
__global__ __launch_bounds__(256) void k_ln(
    const float* __restrict__ att, const float* __restrict__ src,
    const float* __restrict__ w1, const float* __restrict__ b1,
    const float* __restrict__ w2, const float* __restrict__ b2,
    float* __restrict__ out)
{
  const size_t base = (size_t)blockIdx.x * 1024;
  const int t = threadIdx.x, lane = t & 63, w = t >> 6;
  float4 a = ((const float4*)(att + base))[t];
  float s = a.x + a.y + a.z + a.w;
  float s2 = a.x * a.x + a.y * a.y + a.z * a.z + a.w * a.w;
#pragma unroll
  for (int off = 1; off < 64; off <<= 1) {
    s += __shfl_xor(s, off);
    s2 += __shfl_xor(s2, off);
  }
  __shared__ float red[16];
  if (lane == 0) { red[w] = s; red[4 + w] = s2; }
  __syncthreads();
  s = red[0] + red[1] + red[2] + red[3];
  s2 = red[4] + red[5] + red[6] + red[7];
  float mu = s * (1.0f / 1024.0f);
  float var = s2 * (1.0f / 1024.0f) - mu * mu;
  float rs = rsqrtf(var + 1e-5f);
  float4 W1 = ((const float4*)w1)[t], B1 = ((const float4*)b1)[t];
  float4 sv = ((const float4*)(src + base))[t];
  float y0 = sv.x + (a.x - mu) * rs * W1.x + B1.x;
  float y1 = sv.y + (a.y - mu) * rs * W1.y + B1.y;
  float y2 = sv.z + (a.z - mu) * rs * W1.z + B1.z;
  float y3 = sv.w + (a.w - mu) * rs * W1.w + B1.w;
  s = y0 + y1 + y2 + y3;
  s2 = y0 * y0 + y1 * y1 + y2 * y2 + y3 * y3;
#pragma unroll
  for (int off = 1; off < 64; off <<= 1) {
    s += __shfl_xor(s, off);
    s2 += __shfl_xor(s2, off);
  }
  if (lane == 0) { red[8 + w] = s; red[12 + w] = s2; }
  __syncthreads();
  s = red[8] + red[9] + red[10] + red[11];
  s2 = red[12] + red[13] + red[14] + red[15];
  mu = s * (1.0f / 1024.0f);
  var = s2 * (1.0f / 1024.0f) - mu * mu;
  rs = rsqrtf(var + 1e-5f);
  float4 W2 = ((const float4*)w2)[t], B2 = ((const float4*)b2)[t];
  float4 o;
  o.x = (y0 - mu) * rs * W2.x + B2.x;
  o.y = (y1 - mu) * rs * W2.y + B2.y;
  o.z = (y2 - mu) * rs * W2.z + B2.z;
  o.w = (y3 - mu) * rs * W2.w + B2.w;
  ((float4*)(out + base))[t] = o;
}

// ---------------------------------------------------------------- launch
extern "C" void kernel_launch(void* const* d_in, const int* in_sizes, int n_in,
                              void* d_out, int out_size, void* d_ws, size_t ws_size,
                              hipStream_t stream) {
  const float* src = (const float*)d_in[0];
  const float* Wq  = (const float*)d_in[1];
  const float* Wk  = (const float*)d_in[2];
  const float* Wv  = (const float*)d_in[3];
  const float* l1w = (const float*)d_in[4];
  const float* l1b = (const float*)d_in[5];
  const float* l2w = (const float*)d_in[6];
  const float* l2b = (const float*)d_in[7];
  float* Xout = (float*)d_out;                       // 8,388,608 f32
  float* Aout = Xout + (size_t)NROWS * D_MODEL;      // 16,777,216 f32

  // workspace layout (134 MB total)
  char* ws = (char*)d_ws;
  f16* srch = (f16*)ws;                          // 16 MB  (8192x1024 f16)
  f16* wt   = (f16*)(ws + (16u << 20));          //  6 MB  (3 x 1024x1024 f16, transposed)
  f16* qt   = (f16*)(ws + (22u << 20));          // 16 MB
  f16* kt   = (f16*)(ws + (38u << 20));          // 16 MB
  f16* vtT  = (f16*)(ws + (54u << 20));          // 16 MB  (B,D,S)
  f16* abf  = (f16*)(ws + (70u << 20));          // 32 MB  (B,S,S f16)
  float* att = (float*)(ws + (102u << 20));      // 32 MB  (B,S,D f32)

  k_cast_f16<<<4096, 256, 0, stream>>>(src, srch);
  k_castT<<<dim3(16, 16, 3), 256, 0, stream>>>(Wq, Wk, Wv, wt);
  k_gemm_qkv<<<dim3(64, 8, 3), 256, 0, stream>>>(srch, wt, qt, kt, vtT);
  // scores = Qt*Kt^T / 32 -> written straight into d_out's `a` region
  k_gemm_f32<<<dim3(16, 16, 4), 256, 0, stream>>>(
      qt, kt, Aout, 1024, 1024, 1024, 2048, 0.03125f,
      (size_t)1 << 21, (size_t)1 << 21, (size_t)1 << 22);
  k_softmax<<<NROWS, 256, 0, stream>>>(Aout, abf);
  // att = a * Vt
  k_gemm_f32<<<dim3(16, 8, 4), 256, 0, stream>>>(
      abf, vtT, att, 2048, 2048, 2048, 1024, 1.0f,
      (size_t)1 << 22, (size_t)1 << 21, (size_t)1 << 21);
  k_ln<<<NROWS, 256, 0, stream>>>(att, src, l1w, l1b, l2w, l2b, Xout);
}

// Round 2
// 221.912 us; speedup vs baseline: 1.3709x; 1.3709x over previous
//
#include <hip/hip_runtime.h>

typedef _Float16 f16;
typedef __attribute__((ext_vector_type(4))) _Float16 f16x4;
typedef __attribute__((ext_vector_type(8))) _Float16 f16x8;
typedef __attribute__((ext_vector_type(4))) float f32x4;

#define D_MODEL 1024
#define SEQ 2048
#define NBATCH 4
#define NROWS (NBATCH * SEQ)  // 8192

// ---------------------------------------------------------------- utilities
__device__ __forceinline__ void gload16(const void* g, void* l) {
  __builtin_amdgcn_global_load_lds(
      (__attribute__((address_space(1))) void*)(void*)g,
      (__attribute__((address_space(3))) void*)l, 16, 0, 0);
}

// ------------------------------------------------------------- GEMM core
// C[128x128] += A[128xK] * B (B supplied as 128 rows of K, i.e. BT),
// fp16 inputs staged via global_load_lds into XOR-swizzled LDS [128][64].
// 256 threads = 4 waves (2x2 quadrants of 64x64). BK=64, mfma 16x16x32.
// Caller supplies 4 per-thread source pointers per matrix (one per staging
// issue) + per-K-step element strides; this is where layout gathers live.
// LDS swizzle: A chunks (16B) are stored at pos = chunk ^ (row&7);
//              B chunks at pos = chunk ^ ((row>>2)&7).
// The source pointers must already include the matching chunk permutation
// (koffA / koffB below) so that LDS ends up swizzled (m173 pattern).
__device__ __forceinline__ void gemm_core(
    const f16* ga0, const f16* ga1, const f16* ga2, const f16* ga3,
    const f16* gb0, const f16* gb1, const f16* gb2, const f16* gb3,
    int stepA, int stepB, int nsteps, f32x4 acc[4][4], f16* lds)
{
  f16* ldsA = lds;          // [128][64] f16, swizzled
  f16* ldsB = lds + 8192;
  const int t = threadIdx.x, l = t & 63, w = t >> 6;
  const int wr = (w >> 1) << 6, wc = (w & 1) << 6;
  const int fr = l & 15;
  const int g0 = l >> 4;                 // 16B k-chunk within 32-f16 half

  // staging LDS destinations (linear; lane stride 16B)
  char* dA0 = (char*)ldsA + 0 * 4096 + w * 1024 + l * 16;
  char* dA1 = (char*)ldsA + 1 * 4096 + w * 1024 + l * 16;
  char* dA2 = (char*)ldsA + 2 * 4096 + w * 1024 + l * 16;
  char* dA3 = (char*)ldsA + 3 * 4096 + w * 1024 + l * 16;
  char* dB0 = (char*)ldsB + 0 * 4096 + w * 1024 + l * 16;
  char* dB1 = (char*)ldsB + 1 * 4096 + w * 1024 + l * 16;
  char* dB2 = (char*)ldsB + 2 * 4096 + w * 1024 + l * 16;
  char* dB3 = (char*)ldsB + 3 * 4096 + w * 1024 + l * 16;

  // fragment read offsets (f16 units), swizzled
  int aoff[4][2], boff[4][2];
#pragma unroll
  for (int i = 0; i < 4; ++i) {
    const int ra = wr + i * 16 + fr;          // A rows stride 1
    const int keyA = ra & 7;
    aoff[i][0] = ra * 64 + ((g0 ^ keyA) << 3);
    aoff[i][1] = ra * 64 + (((4 + g0) ^ keyA) << 3);
    const int rb = wc + (fr << 2) + i;        // B rows: 4*fr + ni (contig cols!)
    const int keyB = (rb >> 2) & 7;           // == fr&7
    boff[i][0] = rb * 64 + ((g0 ^ keyB) << 3);
    boff[i][1] = rb * 64 + (((4 + g0) ^ keyB) << 3);
  }

  for (int ks = 0; ks < nsteps; ++ks) {
    gload16(ga0, dA0); gload16(ga1, dA1); gload16(ga2, dA2); gload16(ga3, dA3);
    gload16(gb0, dB0); gload16(gb1, dB1); gload16(gb2, dB2); gload16(gb3, dB3);
    ga0 += stepA; ga1 += stepA; ga2 += stepA; ga3 += stepA;
    gb0 += stepB; gb1 += stepB; gb2 += stepB; gb3 += stepB;
    asm volatile("s_waitcnt vmcnt(0)" ::: "memory");
    __syncthreads();
    f16x8 a00 = *(const f16x8*)(ldsA + aoff[0][0]);
    f16x8 a10 = *(const f16x8*)(ldsA + aoff[1][0]);
    f16x8 a20 = *(const f16x8*)(ldsA + aoff[2][0]);
    f16x8 a30 = *(const f16x8*)(ldsA + aoff[3][0]);
    f16x8 b00 = *(const f16x8*)(ldsB + boff[0][0]);
    f16x8 b10 = *(const f16x8*)(ldsB + boff[1][0]);
    f16x8 b20 = *(const f16x8*)(ldsB + boff[2][0]);
    f16x8 b30 = *(const f16x8*)(ldsB + boff[3][0]);
    f16x8 a01 = *(const f16x8*)(ldsA + aoff[0][1]);
    f16x8 a11 = *(const f16x8*)(ldsA + aoff[1][1]);
    f16x8 a21 = *(const f16x8*)(ldsA + aoff[2][1]);
    f16x8 a31 = *(const f16x8*)(ldsA + aoff[3][1]);
    f16x8 b01 = *(const f16x8*)(ldsB + boff[0][1]);
    f16x8 b11 = *(const f16x8*)(ldsB + boff[1][1]);
    f16x8 b21 = *(const f16x8*)(ldsB + boff[2][1]);
    f16x8 b31 = *(const f16x8*)(ldsB + boff[3][1]);

    acc[0][0] = __builtin_amdgcn_mfma_f32_16x16x32_f16(a00, b00, acc[0][0], 0, 0, 0);
    acc[0][1] = __builtin_amdgcn_mfma_f32_16x16x32_f16(a00, b10, acc[0][1], 0, 0, 0);
    acc[0][2] = __builtin_amdgcn_mfma_f32_16x16x32_f16(a00, b20, acc[0][2], 0, 0, 0);
    acc[0][3] = __builtin_amdgcn_mfma_f32_16x16x32_f16(a00, b30, acc[0][3], 0, 0, 0);
    acc[1][0] = __builtin_amdgcn_mfma_f32_16x16x32_f16(a10, b00, acc[1][0], 0, 0, 0);
    acc[1][1] = __builtin_amdgcn_mfma_f32_16x16x32_f16(a10, b10, acc[1][1], 0, 0, 0);
    acc[1][2] = __builtin_amdgcn_mfma_f32_16x16x32_f16(a10, b20, acc[1][2], 0, 0, 0);
    acc[1][3] = __builtin_amdgcn_mfma_f32_16x16x32_f16(a10, b30, acc[1][3], 0, 0, 0);
    acc[2][0] = __builtin_amdgcn_mfma_f32_16x16x32_f16(a20, b00, acc[2][0], 0, 0, 0);
    acc[2][1] = __builtin_amdgcn_mfma_f32_16x16x32_f16(a20, b10, acc[2][1], 0, 0, 0);
    acc[2][2] = __builtin_amdgcn_mfma_f32_16x16x32_f16(a20, b20, acc[2][2], 0, 0, 0);
    acc[2][3] = __builtin_amdgcn_mfma_f32_16x16x32_f16(a20, b30, acc[2][3], 0, 0, 0);
    acc[3][0] = __builtin_amdgcn_mfma_f32_16x16x32_f16(a30, b00, acc[3][0], 0, 0, 0);
    acc[3][1] = __builtin_amdgcn_mfma_f32_16x16x32_f16(a30, b10, acc[3][1], 0, 0, 0);
    acc[3][2] = __builtin_amdgcn_mfma_f32_16x16x32_f16(a30, b20, acc[3][2], 0, 0, 0);
    acc[3][3] = __builtin_amdgcn_mfma_f32_16x16x32_f16(a30, b30, acc[3][3], 0, 0, 0);

    acc[0][0] = __builtin_amdgcn_mfma_f32_16x16x32_f16(a01, b01, acc[0][0], 0, 0, 0);
    acc[0][1] = __builtin_amdgcn_mfma_f32_16x16x32_f16(a01, b11, acc[0][1], 0, 0, 0);
    acc[0][2] = __builtin_amdgcn_mfma_f32_16x16x32_f16(a01, b21, acc[0][2], 0, 0, 0);
    acc[0][3] = __builtin_amdgcn_mfma_f32_16x16x32_f16(a01, b31, acc[0][3], 0, 0, 0);
    acc[1][0] = __builtin_amdgcn_mfma_f32_16x16x32_f16(a11, b01, acc[1][0], 0, 0, 0);
    acc[1][1] = __builtin_amdgcn_mfma_f32_16x16x32_f16(a11, b11, acc[1][1], 0, 0, 0);
    acc[1][2] = __builtin_amdgcn_mfma_f32_16x16x32_f16(a11, b21, acc[1][2], 0, 0, 0);
    acc[1][3] = __builtin_amdgcn_mfma_f32_16x16x32_f16(a11, b31, acc[1][3], 0, 0, 0);
    acc[2][0] = __builtin_amdgcn_mfma_f32_16x16x32_f16(a21, b01, acc[2][0], 0, 0, 0);
    acc[2][1] = __builtin_amdgcn_mfma_f32_16x16x32_f16(a21, b11, acc[2][1], 0, 0, 0);
    acc[2][2] = __builtin_amdgcn_mfma_f32_16x16x32_f16(a21, b21, acc[2][2], 0, 0, 0);
    acc[2][3] = __builtin_amdgcn_mfma_f32_16x16x32_f16(a21, b31, acc[2][3], 0, 0, 0);
    acc[3][0] = __builtin_amdgcn_mfma_f32_16x16x32_f16(a31, b01, acc[3][0], 0, 0, 0);
    acc[3][1] = __builtin_amdgcn_mfma_f32_16x16x32_f16(a31, b11, acc[3][1], 0, 0, 0);
    acc[3][2] = __builtin_amdgcn_mfma_f32_16x16x32_f16(a31, b21, acc[3][2], 0, 0, 0);
    acc[3][3] = __builtin_amdgcn_mfma_f32_16x16x32_f16(a31, b31, acc[3][3], 0, 0, 0);
    __syncthreads();
  }
}

// staging helper indices (must match gemm_core's swizzle)
#define STAGE_IDX                                            \
  const int t = threadIdx.x, l = t & 63, w = t >> 6;         \
  const int koffA = (((l & 7) ^ ((l >> 3) & 7)) << 3);       \
  int rrow[4], koffB[4];                                     \
  _Pragma("unroll")                                          \
  for (int i = 0; i < 4; ++i) {                              \
    rrow[i] = i * 32 + w * 8 + (l >> 3);                     \
    koffB[i] = (((l & 7) ^ ((i * 8 + w * 2 + (l >> 5)) & 7)) << 3); \
  }

// epilogue index helper
#define EPI_IDX                                              \
  const int fr = l & 15;                                     \
  const int wr = ((w >> 1) << 6), wc = ((w & 1) << 6);       \
  const int row0 = (int)blockIdx.x * 128 + wr + ((l >> 4) << 2); \
  const int col0 = (int)blockIdx.y * 128 + wc + (fr << 2);

// ------------------------------------------------- GEMM1: QKV projections
// A = srch (8192x1024), B = wt[z] (1024x1024, pre-transposed). Natural out.
__global__ __launch_bounds__(256) void k_gemm_qkv(
    const f16* __restrict__ srch, const f16* __restrict__ wt,
    f16* __restrict__ qp, f16* __restrict__ kp, f16* __restrict__ vp)
{
  __shared__ f16 lds[16384];
  STAGE_IDX
  const int z = blockIdx.z;
  const f16* A  = srch + (size_t)blockIdx.x * 128 * 1024;
  const f16* BT = wt + ((size_t)z << 20) + (size_t)blockIdx.y * 128 * 1024;
  const f16 *ga[4], *gb[4];
#pragma unroll
  for (int i = 0; i < 4; ++i) {
    ga[i] = A + (size_t)rrow[i] * 1024 + koffA;
    gb[i] = BT + (size_t)rrow[i] * 1024 + koffB[i];
  }
  f32x4 acc[4][4];
#pragma unroll
  for (int i = 0; i < 4; ++i)
#pragma unroll
    for (int j = 0; j < 4; ++j) acc[i][j] = f32x4{0.f, 0.f, 0.f, 0.f};
  gemm_core(ga[0], ga[1], ga[2], ga[3], gb[0], gb[1], gb[2], gb[3],
            64, 64, 16, acc, lds);
  EPI_IDX
  f16* dst = (z == 0) ? qp : (z == 1 ? kp : vp);
#pragma unroll
  for (int mi = 0; mi < 4; ++mi)
#pragma unroll
    for (int q = 0; q < 4; ++q) {
      f16x4 o = {(f16)acc[mi][0][q], (f16)acc[mi][1][q],
                 (f16)acc[mi][2][q], (f16)acc[mi][3][q]};
      *(f16x4*)(dst + (size_t)(row0 + mi * 16 + q) * 1024 + col0) = o;
    }
}

// --------------------------------- GEMM2: scores = Qt*Kt^T/32 (gather-staged)
// Reads natural q_proj/k_proj; the head-scramble is applied in the per-lane
// global staging addresses (scrambled row sp gathers 64-wide natural chunks).
__global__ __launch_bounds__(256) void k_gemm_scores(
    const f16* __restrict__ qp, const f16* __restrict__ kp,
    float* __restrict__ out)
{
  __shared__ f16 lds[16384];
  STAGE_IDX
  const int b = blockIdx.z;
  const f16* qb = qp + ((size_t)b << 21);
  const f16* kb = kp + ((size_t)b << 21);
  const f16 *ga[4], *gb[4];
#pragma unroll
  for (int i = 0; i < 4; ++i) {
    const int spA = blockIdx.x * 128 + rrow[i];
    ga[i] = qb + (size_t)((spA & 127) << 4) * 1024 + ((spA >> 7) << 6) + koffA;
    const int spB = blockIdx.y * 128 + rrow[i];
    gb[i] = kb + (size_t)((spB & 127) << 4) * 1024 + ((spB >> 7) << 6) + koffB[i];
  }
  f32x4 acc[4][4];
#pragma unroll
  for (int i = 0; i < 4; ++i)
#pragma unroll
    for (int j = 0; j < 4; ++j) acc[i][j] = f32x4{0.f, 0.f, 0.f, 0.f};
  gemm_core(ga[0], ga[1], ga[2], ga[3], gb[0], gb[1], gb[2], gb[3],
            1024, 1024, 16, acc, lds);
  EPI_IDX
  float* Cb = out + ((size_t)b << 22);
#pragma unroll
  for (int mi = 0; mi < 4; ++mi)
#pragma unroll
    for (int q = 0; q < 4; ++q) {
      float4 o = {acc[mi][0][q] * 0.03125f, acc[mi][1][q] * 0.03125f,
                  acc[mi][2][q] * 0.03125f, acc[mi][3][q] * 0.03125f};
      *(float4*)(Cb + (size_t)(row0 + mi * 16 + q) * 2048 + col0) = o;
    }
}

// ------------------------------------------------- GEMM3: att = a * Vt
__global__ __launch_bounds__(256) void k_gemm_att(
    const f16* __restrict__ abf, const f16* __restrict__ vtT,
    float* __restrict__ out)
{
  __shared__ f16 lds[16384];
  STAGE_IDX
  const int b = blockIdx.z;
  const f16* ab = abf + ((size_t)b << 22);
  const f16* vb = vtT + ((size_t)b << 21);
  const f16 *ga[4], *gb[4];
#pragma unroll
  for (int i = 0; i < 4; ++i) {
    ga[i] = ab + (size_t)(blockIdx.x * 128 + rrow[i]) * 2048 + koffA;
    gb[i] = vb + (size_t)(blockIdx.y * 128 + rrow[i]) * 2048 + koffB[i];
  }
  f32x4 acc[4][4];
#pragma unroll
  for (int i = 0; i < 4; ++i)
#pragma unroll
    for (int j = 0; j < 4; ++j) acc[i][j] = f32x4{0.f, 0.f, 0.f, 0.f};
  gemm_core(ga[0], ga[1], ga[2], ga[3], gb[0], gb[1], gb[2], gb[3],
            64, 64, 32, acc, lds);
  EPI_IDX
  float* Cb = out + ((size_t)b << 21);
#pragma unroll
  for (int mi = 0; mi < 4; ++mi)
#pragma unroll
    for (int q = 0; q < 4; ++q) {
      float4 o = {acc[mi][0][q], acc[mi][1][q], acc[mi][2][q], acc[mi][3][q]};
      *(float4*)(Cb + (size_t)(row0 + mi * 16 + q) * 1024 + col0) = o;
    }
}

// ------------------------------------------- scramble-transpose of V
// vtT[b][dp][sp] = v_proj[b][((sp&127)<<4)|(dp>>6)][((sp>>7)<<6)|(dp&63)]
__global__ __launch_bounds__(256) void k_scrT(const f16* __restrict__ vp,
                                              f16* __restrict__ vtT)
{
  __shared__ f16 tile[64][68];
  const int t = threadIdx.x;
  const int sp0 = blockIdx.x * 64, dp0 = blockIdx.y * 64;
  const int d6 = dp0 >> 6;
  const int jb = (sp0 >> 7) << 6;
  const int sbase = sp0 & 127;
  const f16* src = vp + ((size_t)blockIdx.z << 21);
  f16* dst = vtT + ((size_t)blockIdx.z << 21);
#pragma unroll
  for (int p = 0; p < 2; ++p) {
    const int u = p * 32 + (t >> 3);
    const int s = ((sbase + u) << 4) | d6;
    const int c = (t & 7) << 3;
    f16x8 v = *(const f16x8*)(src + (size_t)s * 1024 + jb + c);
    *(f16x4*)&tile[u][c]     = f16x4{v[0], v[1], v[2], v[3]};
    *(f16x4*)&tile[u][c + 4] = f16x4{v[4], v[5], v[6], v[7]};
  }
  __syncthreads();
#pragma unroll
  for (int p = 0; p < 2; ++p) {
    const int c = p * 32 + (t >> 3);   // dp - dp0
    const int v0 = (t & 7) << 3;       // sp - sp0
    f16x8 o;
#pragma unroll
    for (int j = 0; j < 8; ++j) o[j] = tile[v0 + j][c];
    *(f16x8*)(dst + (size_t)(dp0 + c) * 2048 + sp0 + v0) = o;
  }
}

// -------------------------------------------------------------- casts
__global__ __launch_bounds__(256) void k_cast_f16(const float* __restrict__ in,
                                                  f16* __restrict__ out)
{
  const size_t i = (size_t)blockIdx.x * 256 + threadIdx.x;
  const float4* p = (const float4*)in;
  float4 v0 = p[2 * i], v1 = p[2 * i + 1];
  f16x8 o;
  o[0] = (f16)v0.x; o[1] = (f16)v0.y; o[2] = (f16)v0.z; o[3] = (f16)v0.w;
  o[4] = (f16)v1.x; o[5] = (f16)v1.y; o[6] = (f16)v1.z; o[7] = (f16)v1.w;
  *(f16x8*)(out + 8 * i) = o;
}

__global__ __launch_bounds__(256) void k_castT(
    const float* __restrict__ w0, const float* __restrict__ w1,
    const float* __restrict__ w2, f16* __restrict__ out)
{
  const float* in = (blockIdx.z == 0) ? w0 : (blockIdx.z == 1 ? w1 : w2);
  f16* o = out + ((size_t)blockIdx.z << 20);
  __shared__ f16 tile[64][65];
  const int t = threadIdx.x;
  const int rr = t >> 4, c4 = (t & 15) * 4;
  const int r0 = blockIdx.x * 64, c0 = blockIdx.y * 64;
#pragma unroll
  for (int i = 0; i < 4; ++i) {
    float4 f = *(const float4*)(in + (size_t)(r0 + rr + 16 * i) * 1024 + c0 + c4);
    tile[rr + 16 * i][c4 + 0] = (f16)f.x;
    tile[rr + 16 * i][c4 + 1] = (f16)f.y;
    tile[rr + 16 * i][c4 + 2] = (f16)f.z;
    tile[rr + 16 * i][c4 + 3] = (f16)f.w;
  }
  __syncthreads();
#pragma unroll
  for (int i = 0; i < 4; ++i) {
    const int n = c0 + rr + 16 * i;
    f16* dst = o + (size_t)n * 1024 + r0 + c4;
    dst[0] = tile[c4 + 0][rr + 16 * i];
    dst[1] = tile[c4 + 1][rr + 16 * i];
    dst[2] = tile[c4 + 2][rr + 16 * i];
    dst[3] = tile[c4 + 3][rr + 16 * i];
  }
}

// ------------------------------------------------------- softmax (in place)
__global__ __launch_bounds__(256) void k_softmax(float* __restrict__ sc,
                                                 f16* __restrict__ abf)
{
  const size_t base = (size_t)blockIdx.x * 2048;
  const int t = threadIdx.x, lane = t & 63, w = t >> 6;
  float4* p = (float4*)(sc + base);
  float4 v0 = p[2 * t], v1 = p[2 * t + 1];
  float m = fmaxf(fmaxf(fmaxf(v0.x, v0.y), fmaxf(v0.z, v0.w)),
                  fmaxf(fmaxf(v1.x, v1.y), fmaxf(v1.z, v1.w)));
#pragma unroll
  for (int off = 1; off < 64; off <<= 1) m = fmaxf(m, __shfl_xor(m, off));
  __shared__ float red[8];
  if (lane == 0) red[w] = m;
  __syncthreads();
  m = fmaxf(fmaxf(red[0], red[1]), fmaxf(red[2], red[3]));
  v0.x = __expf(v0.x - m); v0.y = __expf(v0.y - m);
  v0.z = __expf(v0.z - m); v0.w = __expf(v0.w - m);
  v1.x = __expf(v1.x - m); v1.y = __expf(v1.y - m);
  v1.z = __expf(v1.z - m); v1.w = __expf(v1.w - m);
  float s = v0.x + v0.y + v0.z + v0.w + v1.x + v1.y + v1.z + v1.w;
#pragma unroll
  for (int off = 1; off < 64; off <<= 1) s += __shfl_xor(s, off);
  if (lane == 0) red[4 + w] = s;
  __syncthreads();
  s = red[4] + red[5] + red[6] + red[7];
  const float inv = 1.0f / s;
  v0.x *= inv; v0.y *= inv; v0.z *= inv; v0.w *= inv;
  v1.x *= inv; v1.y *= inv; v1.z *= inv; v1.w *= inv;
  p[2 * t] = v0; p[2 * t + 1] = v1;
  f16x8 o;
  o[0] = (f16)v0.x; o[1] = (f16)v0.y; o[2] = (f16)v0.z; o[3] = (f16)v0.w;
  o[4] = (f16)v1.x; o[5] = (f16)v1.y; o[6] = (f16)v1.z; o[7] = (f16)v1.w;
  *(f16x8*)(abf + base + (size_t)t * 8) = o;
}

// --------------------------------------------- fused LN1 + add + LN2
__global__ __launch_bounds__(256) void k_ln(
    const float* __restrict__ att, const float* __restrict__ src,
    const float* __restrict__ w1, const float* __restrict__ b1,
    const float* __restrict__ w2, const float* __restrict__ b2,
    float* __restrict__ out)
{
  const size_t base = (size_t)blockIdx.x * 1024;
  const int t = threadIdx.x, lane = t & 63, w = t >> 6;
  float4 a = ((const float4*)(att + base))[t];
  float s = a.x + a.y + a.z + a.w;
  float s2 = a.x * a.x + a.y * a.y + a.z * a.z + a.w * a.w;
#pragma unroll
  for (int off = 1; off < 64; off <<= 1) {
    s += __shfl_xor(s, off);
    s2 += __shfl_xor(s2, off);
  }
  __shared__ float red[16];
  if (lane == 0) { red[w] = s; red[4 + w] = s2; }
  __syncthreads();
  s = red[0] + red[1] + red[2] + red[3];
  s2 = red[4] + red[5] + red[6] + red[7];
  float mu = s * (1.0f / 1024.0f);
  float var = s2 * (1.0f / 1024.0f) - mu * mu;
  float rs = rsqrtf(var + 1e-5f);
  float4 W1 = ((const float4*)w1)[t], B1 = ((const float4*)b1)[t];
  float4 sv = ((const float4*)(src + base))[t];
  float y0 = sv.x + (a.x - mu) * rs * W1.x + B1.x;
  float y1 = sv.y + (a.y - mu) * rs * W1.y + B1.y;
  float y2 = sv.z + (a.z - mu) * rs * W1.z + B1.z;
  float y3 = sv.w + (a.w - mu) * rs * W1.w + B1.w;
  s = y0 + y1 + y2 + y3;
  s2 = y0 * y0 + y1 * y1 + y2 * y2 + y3 * y3;
#pragma unroll
  for (int off = 1; off < 64; off <<= 1) {
    s += __shfl_xor(s, off);
    s2 += __shfl_xor(s2, off);
  }
  if (lane == 0) { red[8 + w] = s; red[12 + w] = s2; }
  __syncthreads();
  s = red[8] + red[9] + red[10] + red[11];
  s2 = red[12] + red[13] + red[14] + red[15];
  mu = s * (1.0f / 1024.0f);
  var = s2 * (1.0f / 1024.0f) - mu * mu;
  rs = rsqrtf(var + 1e-5f);
  float4 W2 = ((const float4*)w2)[t], B2 = ((const float4*)b2)[t];
  float4 o;
  o.x = (y0 - mu) * rs * W2.x + B2.x;
  o.y = (y1 - mu) * rs * W2.y + B2.y;
  o.z = (y2 - mu) * rs * W2.z + B2.z;
  o.w = (y3 - mu) * rs * W2.w + B2.w;
  ((float4*)(out + base))[t] = o;
}

// ---------------------------------------------------------------- launch
extern "C" void kernel_launch(void* const* d_in, const int* in_sizes, int n_in,
                              void* d_out, int out_size, void* d_ws, size_t ws_size,
                              hipStream_t stream) {
  const float* src = (const float*)d_in[0];
  const float* Wq  = (const float*)d_in[1];
  const float* Wk  = (const float*)d_in[2];
  const float* Wv  = (const float*)d_in[3];
  const float* l1w = (const float*)d_in[4];
  const float* l1b = (const float*)d_in[5];
  const float* l2w = (const float*)d_in[6];
  const float* l2b = (const float*)d_in[7];
  float* Xout = (float*)d_out;
  float* Aout = Xout + (size_t)NROWS * D_MODEL;

  // workspace (128 MB): region [0,32MB) holds srch(16)+wt(6) early, att f32 late
  char* ws = (char*)d_ws;
  f16* srch  = (f16*)ws;                     // 16 MB, dead after k_gemm_qkv
  f16* wt    = (f16*)(ws + (16u << 20));     //  6 MB, dead after k_gemm_qkv
  float* att = (float*)ws;                   // 32 MB, overlays srch+wt
  f16* qp    = (f16*)(ws + (32u << 20));     // 16 MB
  f16* kp    = (f16*)(ws + (48u << 20));     // 16 MB
  f16* vp    = (f16*)(ws + (64u << 20));     // 16 MB
  f16* vtT   = (f16*)(ws + (80u << 20));     // 16 MB
  f16* abf   = (f16*)(ws + (96u << 20));     // 32 MB

  k_cast_f16<<<4096, 256, 0, stream>>>(src, srch);
  k_castT<<<dim3(16, 16, 3), 256, 0, stream>>>(Wq, Wk, Wv, wt);
  k_gemm_qkv<<<dim3(64, 8, 3), 256, 0, stream>>>(srch, wt, qp, kp, vp);
  k_scrT<<<dim3(32, 16, 4), 256, 0, stream>>>(vp, vtT);
  k_gemm_scores<<<dim3(16, 16, 4), 256, 0, stream>>>(qp, kp, Aout);
  k_softmax<<<NROWS, 256, 0, stream>>>(Aout, abf);
  k_gemm_att<<<dim3(16, 8, 4), 256, 0, stream>>>(abf, vtT, att);
  k_ln<<<NROWS, 256, 0, stream>>>(att, src, l1w, l1b, l2w, l2b, Xout);
}

// Round 3
// 209.133 us; speedup vs baseline: 1.4546x; 1.0611x over previous
//
#include <hip/hip_runtime.h>

typedef _Float16 f16;
typedef __attribute__((ext_vector_type(2))) _Float16 f16x2;
typedef __attribute__((ext_vector_type(4))) _Float16 f16x4;
typedef __attribute__((ext_vector_type(8))) _Float16 f16x8;
typedef __attribute__((ext_vector_type(4))) float f32x4;

#define D_MODEL 1024
#define SEQ 2048
#define NBATCH 4
#define NROWS (NBATCH * SEQ)  // 8192

// ---------------------------------------------------------------- utilities
__device__ __forceinline__ void gload16(const void* g, void* l) {
  __builtin_amdgcn_global_load_lds(
      (__attribute__((address_space(1))) void*)(void*)g,
      (__attribute__((address_space(3))) void*)l, 16, 0, 0);
}

#define BAR __builtin_amdgcn_s_barrier()
#define LGK0                                              \
  asm volatile("s_waitcnt lgkmcnt(0)" ::: "memory");      \
  __builtin_amdgcn_sched_barrier(0)
#define PRIO1 __builtin_amdgcn_s_setprio(1)
#define PRIO0 __builtin_amdgcn_s_setprio(0)

// ---------------------------------------------------------- 8-wave GEMM core
// BM=256, BN in {256,128}, BK=64, 512 threads (8 waves = 2M x 4N), f16 MFMA
// 16x16x32, fp32 acc. LDS double-buffered: slot = A[256][64] + B[BN][64],
// XOR-swizzled via pre-swizzled global source (keyA=row&7, keyB=(row>>2)&7).
// 4 phases per K-tile; tile kt+2 is staged into the CURRENT slot at p3 (B,
// after B's last read at p2) and p4 (A, after A's last read at p3); the
// counted vmcnt(8|6) at p4 (= exactly the loads just issued) guarantees tile
// kt+1 is fully landed with ~1 K-tile of prefetch slack. Never vmcnt(0).
template <int BN>
__device__ __forceinline__ void gemm8_core(
    const f16* aP0, const f16* aP1, const f16* aP2, const f16* aP3,
    const f16* bP0, const f16* bP1, const f16* bP2, const f16* bP3,
    int stepA, int stepB, int NT, f16* lds, f32x4* acc)
{
  constexpr int NJ = BN / 128;        // n-tiles per n-half per wave (2|1)
  constexpr int NACC = 2 * NJ;        // acc columns (4|2)
  constexpr int SLOT = 16384 + BN * 64;  // f16 units per slot
  const int t = threadIdx.x, l = t & 63;
  const int w = t >> 6, wm = w >> 2, wn = w & 3;
  const int fr = l & 15, g0 = l >> 4;

  // fragment LDS offsets (f16 units within slot), swizzled
  int aof[2][4][2], bof[2][NJ][2];
#pragma unroll
  for (int mh = 0; mh < 2; ++mh)
#pragma unroll
    for (int mi = 0; mi < 4; ++mi)
#pragma unroll
      for (int kh = 0; kh < 2; ++kh) {
        const int ra = wm * 128 + mh * 64 + mi * 16 + fr;
        aof[mh][mi][kh] = ra * 64 + (((g0 + kh * 4) ^ (ra & 7)) << 3);
      }
#pragma unroll
  for (int nh = 0; nh < 2; ++nh)
#pragma unroll
    for (int j = 0; j < NJ; ++j)
#pragma unroll
      for (int kh = 0; kh < 2; ++kh) {
        const int rb = (BN == 256) ? (wn * 64 + fr * 4 + nh * 2 + j)
                                   : (wn * 32 + fr * 2 + nh);
        bof[nh][j][kh] = rb * 64 + (((g0 + kh * 4) ^ ((rb >> 2) & 7)) << 3);
      }
#pragma unroll
  for (int i = 0; i < 8 * NACC; ++i) acc[i] = f32x4{0.f, 0.f, 0.f, 0.f};

  f16x8 fa[4][2];      // A frags of current m-half
  f16x8 fb[2][NJ][2];  // B frags [n-half][j][kh]

#define STAGE_A(SL)                                  \
  {                                                  \
    f16* d = lds + (SL) * SLOT + t * 8;              \
    gload16(aP0, d);                                 \
    gload16(aP1, d + 4096);                          \
    gload16(aP2, d + 8192);                          \
    gload16(aP3, d + 12288);                         \
  }
#define STAGE_B(SL)                                  \
  {                                                  \
    f16* d = lds + (SL) * SLOT + 16384 + t * 8;      \
    gload16(bP0, d);                                 \
    gload16(bP1, d + 4096);                          \
    if constexpr (BN == 256) {                       \
      gload16(bP2, d + 8192);                        \
      gload16(bP3, d + 12288);                       \
    }                                                \
  }
#define ADV                                          \
  aP0 += stepA; aP1 += stepA; aP2 += stepA; aP3 += stepA; \
  bP0 += stepB; bP1 += stepB;                        \
  if constexpr (BN == 256) { bP2 += stepB; bP3 += stepB; }
#define VMC                                                        \
  if constexpr (BN == 256) {                                       \
    asm volatile("s_waitcnt vmcnt(8)" ::: "memory");               \
  } else {                                                         \
    asm volatile("s_waitcnt vmcnt(6)" ::: "memory");               \
  }
#define LOAD_A(MH)                                   \
  _Pragma("unroll") for (int mi = 0; mi < 4; ++mi)   \
  _Pragma("unroll") for (int kh = 0; kh < 2; ++kh)   \
      fa[mi][kh] = *(const f16x8*)(LA + aof[MH][mi][kh]);
#define LOAD_B(NH)                                   \
  _Pragma("unroll") for (int j = 0; j < NJ; ++j)     \
  _Pragma("unroll") for (int kh = 0; kh < 2; ++kh)   \
      fb[NH][j][kh] = *(const f16x8*)(LB + bof[NH][j][kh]);
#define MFMA_BLK(MH, NH)                                                    \
  _Pragma("unroll") for (int mi = 0; mi < 4; ++mi)                          \
  _Pragma("unroll") for (int j = 0; j < NJ; ++j)                            \
  _Pragma("unroll") for (int kh = 0; kh < 2; ++kh)                          \
      acc[((MH)*4 + mi) * NACC + (NH)*NJ + j] =                             \
          __builtin_amdgcn_mfma_f32_16x16x32_f16(                           \
              fa[mi][kh], fb[NH][j][kh],                                    \
              acc[((MH)*4 + mi) * NACC + (NH)*NJ + j], 0, 0, 0);

  (void)bP2; (void)bP3;
  // prologue: stage tiles 0 and 1 completely, wait for tile 0
  STAGE_A(0); STAGE_B(0); ADV;
  STAGE_A(1); STAGE_B(1); ADV;
  VMC;
  BAR;

  for (int kt = 0; kt < NT; ++kt) {
    const int sl = kt & 1;
    const f16* LA = lds + sl * SLOT;
    const f16* LB = LA + 16384;
    // p1
    LOAD_A(0); LOAD_B(0);
    BAR; LGK0;
    PRIO1; MFMA_BLK(0, 0); PRIO0; BAR;
    // p2
    LOAD_B(1);
    BAR; LGK0;
    PRIO1; MFMA_BLK(0, 1); PRIO0; BAR;
    // p3: refill current slot's B with tile kt+2 (B last read at p2)
    LOAD_A(1);
    STAGE_B(sl);
    BAR; LGK0;
    PRIO1; MFMA_BLK(1, 0); PRIO0; BAR;
    // p4: refill current slot's A with tile kt+2 (A last read at p3)
    STAGE_A(sl);
    if (kt + 3 < NT) { ADV; }
    VMC;  // tile kt+1 fully landed; kt+2's 8|6 loads stay in flight
    BAR;
    PRIO1; MFMA_BLK(1, 1); PRIO0; BAR;
  }
#undef STAGE_A
#undef STAGE_B
#undef ADV
#undef VMC
#undef LOAD_A
#undef LOAD_B
#undef MFMA_BLK
}

// ------------------------------------------------- GEMM1: QKV (N merged 3072)
__global__ __launch_bounds__(512, 2) void k_qkv3(
    const f16* __restrict__ srch, const f16* __restrict__ wt,
    f16* __restrict__ qp, f16* __restrict__ kp, f16* __restrict__ vp)
{
  __shared__ f16 lds[2 * (16384 + 256 * 64)];
  const int t = threadIdx.x, l = t & 63;
  const int w = t >> 6, wm = w >> 2, wn = w & 3;
  const int fr = l & 15, g0 = l >> 4, c = t & 7;
  const f16 *aP[4], *bP[4];
#pragma unroll
  for (int i = 0; i < 4; ++i) {
    const int rl = i * 64 + (t >> 3);
    aP[i] = srch + (size_t)(blockIdx.x * 256 + rl) * 1024 + ((c ^ (rl & 7)) << 3);
    bP[i] = wt + (size_t)(blockIdx.y * 256 + rl) * 1024 + ((c ^ ((rl >> 2) & 7)) << 3);
  }
  f32x4 acc[32];
  gemm8_core<256>(aP[0], aP[1], aP[2], aP[3], bP[0], bP[1], bP[2], bP[3],
                  64, 64, 16, lds, acc);
  const int z = blockIdx.y >> 2;
  f16* dst = (z == 0) ? qp : (z == 1 ? kp : vp);
  const int col = (blockIdx.y & 3) * 256 + wn * 64 + fr * 4;
#pragma unroll
  for (int mi = 0; mi < 8; ++mi)
#pragma unroll
    for (int q = 0; q < 4; ++q) {
      const int row = blockIdx.x * 256 + wm * 128 + mi * 16 + g0 * 4 + q;
      f16x4 o = {(f16)acc[mi * 4 + 0][q], (f16)acc[mi * 4 + 1][q],
                 (f16)acc[mi * 4 + 2][q], (f16)acc[mi * 4 + 3][q]};
      *(f16x4*)(dst + (size_t)row * 1024 + col) = o;
    }
}

// --------------------------- GEMM2: scores = Qt*Kt^T/32, f16 out (gathered)
__global__ __launch_bounds__(512, 2) void k_scores(
    const f16* __restrict__ qp, const f16* __restrict__ kp,
    f16* __restrict__ abf)
{
  __shared__ f16 lds[2 * (16384 + 256 * 64)];
  const int t = threadIdx.x, l = t & 63;
  const int w = t >> 6, wm = w >> 2, wn = w & 3;
  const int fr = l & 15, g0 = l >> 4, c = t & 7;
  const int b = blockIdx.z;
  const f16* qb = qp + ((size_t)b << 21);
  const f16* kb = kp + ((size_t)b << 21);
  const f16 *aP[4], *bP[4];
#pragma unroll
  for (int i = 0; i < 4; ++i) {
    const int rl = i * 64 + (t >> 3);
    const int spA = blockIdx.x * 256 + rl;
    aP[i] = qb + (size_t)((spA & 127) << 4) * 1024 + ((spA >> 7) << 6) +
            ((c ^ (rl & 7)) << 3);
    const int spB = blockIdx.y * 256 + rl;
    bP[i] = kb + (size_t)((spB & 127) << 4) * 1024 + ((spB >> 7) << 6) +
            ((c ^ ((rl >> 2) & 7)) << 3);
  }
  f32x4 acc[32];
  gemm8_core<256>(aP[0], aP[1], aP[2], aP[3], bP[0], bP[1], bP[2], bP[3],
                  1024, 1024, 16, lds, acc);
  f16* Cb = abf + ((size_t)b << 22);
  const int col = blockIdx.y * 256 + wn * 64 + fr * 4;
#pragma unroll
  for (int mi = 0; mi < 8; ++mi)
#pragma unroll
    for (int q = 0; q < 4; ++q) {
      const int row = blockIdx.x * 256 + wm * 128 + mi * 16 + g0 * 4 + q;
      f16x4 o = {(f16)(acc[mi * 4 + 0][q] * 0.03125f),
                 (f16)(acc[mi * 4 + 1][q] * 0.03125f),
                 (f16)(acc[mi * 4 + 2][q] * 0.03125f),
                 (f16)(acc[mi * 4 + 3][q] * 0.03125f)};
      *(f16x4*)(Cb + (size_t)row * 2048 + col) = o;
    }
}

// ------------------------------------- GEMM3: att = a * Vt, f16 out, BN=128
__global__ __launch_bounds__(512, 2) void k_att(
    const f16* __restrict__ abf, const f16* __restrict__ vtT,
    f16* __restrict__ attb)
{
  __shared__ f16 lds[2 * (16384 + 128 * 64)];
  const int t = threadIdx.x, l = t & 63;
  const int w = t >> 6, wm = w >> 2, wn = w & 3;
  const int fr = l & 15, g0 = l >> 4, c = t & 7;
  const int b = blockIdx.z;
  const f16* ab = abf + ((size_t)b << 22);
  const f16* vb = vtT + ((size_t)b << 21);
  const f16 *aP[4], *bP[2];
#pragma unroll
  for (int i = 0; i < 4; ++i) {
    const int rl = i * 64 + (t >> 3);
    aP[i] = ab + (size_t)(blockIdx.x * 256 + rl) * 2048 + ((c ^ (rl & 7)) << 3);
  }
#pragma unroll
  for (int i = 0; i < 2; ++i) {
    const int rl = i * 64 + (t >> 3);
    bP[i] = vb + (size_t)(blockIdx.y * 128 + rl) * 2048 +
            ((c ^ ((rl >> 2) & 7)) << 3);
  }
  f32x4 acc[16];
  gemm8_core<128>(aP[0], aP[1], aP[2], aP[3], bP[0], bP[1], bP[0], bP[0],
                  64, 64, 32, lds, acc);
  f16* Cb = attb + ((size_t)b << 21);
  const int col = blockIdx.y * 128 + wn * 32 + fr * 2;
#pragma unroll
  for (int mi = 0; mi < 8; ++mi)
#pragma unroll
    for (int q = 0; q < 4; ++q) {
      const int row = blockIdx.x * 256 + wm * 128 + mi * 16 + g0 * 4 + q;
      f16x2 o = {(f16)acc[mi * 2 + 0][q], (f16)acc[mi * 2 + 1][q]};
      *(f16x2*)(Cb + (size_t)row * 1024 + col) = o;
    }
}

// ------------------------------------------- scramble-transpose of V
__global__ __launch_bounds__(256) void k_scrT(const f16* __restrict__ vp,
                                              f16* __restrict__ vtT)
{
  __shared__ f16 tile[64][68];
  const int t = threadIdx.x;
  const int sp0 = blockIdx.x * 64, dp0 = blockIdx.y * 64;
  const int d6 = dp0 >> 6;
  const int jb = (sp0 >> 7) << 6;
  const int sbase = sp0 & 127;
  const f16* src = vp + ((size_t)blockIdx.z << 21);
  f16* dst = vtT + ((size_t)blockIdx.z << 21);
#pragma unroll
  for (int p = 0; p < 2; ++p) {
    const int u = p * 32 + (t >> 3);
    const int s = ((sbase + u) << 4) | d6;
    const int c = (t & 7) << 3;
    f16x8 v = *(const f16x8*)(src + (size_t)s * 1024 + jb + c);
    *(f16x4*)&tile[u][c]     = f16x4{v[0], v[1], v[2], v[3]};
    *(f16x4*)&tile[u][c + 4] = f16x4{v[4], v[5], v[6], v[7]};
  }
  __syncthreads();
#pragma unroll
  for (int p = 0; p < 2; ++p) {
    const int cc = p * 32 + (t >> 3);
    const int v0 = (t & 7) << 3;
    f16x8 o;
#pragma unroll
    for (int j = 0; j < 8; ++j) o[j] = tile[v0 + j][cc];
    *(f16x8*)(dst + (size_t)(dp0 + cc) * 2048 + sp0 + v0) = o;
  }
}

// -------------------------------------------------------------- casts
__global__ __launch_bounds__(256) void k_cast_f16(const float* __restrict__ in,
                                                  f16* __restrict__ out)
{
  const size_t i = (size_t)blockIdx.x * 256 + threadIdx.x;
  const float4* p = (const float4*)in;
  float4 v0 = p[2 * i], v1 = p[2 * i + 1];
  f16x8 o;
  o[0] = (f16)v0.x; o[1] = (f16)v0.y; o[2] = (f16)v0.z; o[3] = (f16)v0.w;
  o[4] = (f16)v1.x; o[5] = (f16)v1.y; o[6] = (f16)v1.z; o[7] = (f16)v1.w;
  *(f16x8*)(out + 8 * i) = o;
}

__global__ __launch_bounds__(256) void k_castT(
    const float* __restrict__ w0, const float* __restrict__ w1,
    const float* __restrict__ w2, f16* __restrict__ out)
{
  const float* in = (blockIdx.z == 0) ? w0 : (blockIdx.z == 1 ? w1 : w2);
  f16* o = out + ((size_t)blockIdx.z << 20);
  __shared__ f16 tile[64][65];
  const int t = threadIdx.x;
  const int rr = t >> 4, c4 = (t & 15) * 4;
  const int r0 = blockIdx.x * 64, c0 = blockIdx.y * 64;
#pragma unroll
  for (int i = 0; i < 4; ++i) {
    float4 f = *(const float4*)(in + (size_t)(r0 + rr + 16 * i) * 1024 + c0 + c4);
    tile[rr + 16 * i][c4 + 0] = (f16)f.x;
    tile[rr + 16 * i][c4 + 1] = (f16)f.y;
    tile[rr + 16 * i][c4 + 2] = (f16)f.z;
    tile[rr + 16 * i][c4 + 3] = (f16)f.w;
  }
  __syncthreads();
#pragma unroll
  for (int i = 0; i < 4; ++i) {
    const int n = c0 + rr + 16 * i;
    f16* dst = o + (size_t)n * 1024 + r0 + c4;
    dst[0] = tile[c4 + 0][rr + 16 * i];
    dst[1] = tile[c4 + 1][rr + 16 * i];
    dst[2] = tile[c4 + 2][rr + 16 * i];
    dst[3] = tile[c4 + 3][rr + 16 * i];
  }
}

// ------------------- softmax: reads f16 scores, writes f32 a + f16 in place
__global__ __launch_bounds__(256) void k_softmax(float* __restrict__ out,
                                                 f16* __restrict__ abf)
{
  const size_t base = (size_t)blockIdx.x * 2048;
  const int t = threadIdx.x, lane = t & 63, w = t >> 6;
  f16x8 v = *(const f16x8*)(abf + base + (size_t)t * 8);
  float x[8];
#pragma unroll
  for (int j = 0; j < 8; ++j) x[j] = (float)v[j];
  float m = fmaxf(fmaxf(fmaxf(x[0], x[1]), fmaxf(x[2], x[3])),
                  fmaxf(fmaxf(x[4], x[5]), fmaxf(x[6], x[7])));
#pragma unroll
  for (int off = 1; off < 64; off <<= 1) m = fmaxf(m, __shfl_xor(m, off));
  __shared__ float red[8];
  if (lane == 0) red[w] = m;
  __syncthreads();
  m = fmaxf(fmaxf(red[0], red[1]), fmaxf(red[2], red[3]));
  float s = 0.f;
#pragma unroll
  for (int j = 0; j < 8; ++j) { x[j] = __expf(x[j] - m); s += x[j]; }
#pragma unroll
  for (int off = 1; off < 64; off <<= 1) s += __shfl_xor(s, off);
  if (lane == 0) red[4 + w] = s;
  __syncthreads();
  s = red[4] + red[5] + red[6] + red[7];
  const float inv = 1.0f / s;
#pragma unroll
  for (int j = 0; j < 8; ++j) x[j] *= inv;
  float4 o0 = {x[0], x[1], x[2], x[3]}, o1 = {x[4], x[5], x[6], x[7]};
  ((float4*)(out + base))[2 * t] = o0;
  ((float4*)(out + base))[2 * t + 1] = o1;
  f16x8 ov;
#pragma unroll
  for (int j = 0; j < 8; ++j) ov[j] = (f16)x[j];
  *(f16x8*)(abf + base + (size_t)t * 8) = ov;
}

// --------------------------------------------- fused LN1 + add + LN2
__global__ __launch_bounds__(256) void k_ln(
    const f16* __restrict__ attb, const float* __restrict__ src,
    const float* __restrict__ w1, const float* __restrict__ b1,
    const float* __restrict__ w2, const float* __restrict__ b2,
    float* __restrict__ out)
{
  const size_t base = (size_t)blockIdx.x * 1024;
  const int t = threadIdx.x, lane = t & 63, w = t >> 6;
  f16x4 a4 = ((const f16x4*)(attb + base))[t];
  float ax = (float)a4[0], ay = (float)a4[1], az = (float)a4[2], aw = (float)a4[3];
  float s = ax + ay + az + aw;
  float s2 = ax * ax + ay * ay + az * az + aw * aw;
#pragma unroll
  for (int off = 1; off < 64; off <<= 1) {
    s += __shfl_xor(s, off);
    s2 += __shfl_xor(s2, off);
  }
  __shared__ float red[16];
  if (lane == 0) { red[w] = s; red[4 + w] = s2; }
  __syncthreads();
  s = red[0] + red[1] + red[2] + red[3];
  s2 = red[4] + red[5] + red[6] + red[7];
  float mu = s * (1.0f / 1024.0f);
  float var = s2 * (1.0f / 1024.0f) - mu * mu;
  float rs = rsqrtf(var + 1e-5f);
  float4 W1 = ((const float4*)w1)[t], B1 = ((const float4*)b1)[t];
  float4 sv = ((const float4*)(src + base))[t];
  float y0 = sv.x + (ax - mu) * rs * W1.x + B1.x;
  float y1 = sv.y + (ay - mu) * rs * W1.y + B1.y;
  float y2 = sv.z + (az - mu) * rs * W1.z + B1.z;
  float y3 = sv.w + (aw - mu) * rs * W1.w + B1.w;
  s = y0 + y1 + y2 + y3;
  s2 = y0 * y0 + y1 * y1 + y2 * y2 + y3 * y3;
#pragma unroll
  for (int off = 1; off < 64; off <<= 1) {
    s += __shfl_xor(s, off);
    s2 += __shfl_xor(s2, off);
  }
  if (lane == 0) { red[8 + w] = s; red[12 + w] = s2; }
  __syncthreads();
  s = red[8] + red[9] + red[10] + red[11];
  s2 = red[12] + red[13] + red[14] + red[15];
  mu = s * (1.0f / 1024.0f);
  var = s2 * (1.0f / 1024.0f) - mu * mu;
  rs = rsqrtf(var + 1e-5f);
  float4 W2 = ((const float4*)w2)[t], B2 = ((const float4*)b2)[t];
  float4 o;
  o.x = (y0 - mu) * rs * W2.x + B2.x;
  o.y = (y1 - mu) * rs * W2.y + B2.y;
  o.z = (y2 - mu) * rs * W2.z + B2.z;
  o.w = (y3 - mu) * rs * W2.w + B2.w;
  ((float4*)(out + base))[t] = o;
}

// ---------------------------------------------------------------- launch
extern "C" void kernel_launch(void* const* d_in, const int* in_sizes, int n_in,
                              void* d_out, int out_size, void* d_ws, size_t ws_size,
                              hipStream_t stream) {
  const float* src = (const float*)d_in[0];
  const float* Wq  = (const float*)d_in[1];
  const float* Wk  = (const float*)d_in[2];
  const float* Wv  = (const float*)d_in[3];
  const float* l1w = (const float*)d_in[4];
  const float* l1b = (const float*)d_in[5];
  const float* l2w = (const float*)d_in[6];
  const float* l2b = (const float*)d_in[7];
  float* Xout = (float*)d_out;
  float* Aout = Xout + (size_t)NROWS * D_MODEL;

  // workspace layout (134 MB, non-overlapping)
  char* ws = (char*)d_ws;
  f16* srch = (f16*)ws;                       // 16 MB (8192x1024)
  f16* wt   = (f16*)(ws + (16u << 20));       //  6 MB (3072x1024, W^T)
  f16* qp   = (f16*)(ws + (22u << 20));       // 16 MB
  f16* kp   = (f16*)(ws + (38u << 20));       // 16 MB
  f16* vp   = (f16*)(ws + (54u << 20));       // 16 MB
  f16* vtT  = (f16*)(ws + (70u << 20));       // 16 MB (B,D,S scrambled-T)
  f16* abf  = (f16*)(ws + (86u << 20));       // 32 MB (B,S,S scores->a f16)
  f16* attb = (f16*)(ws + (118u << 20));      // 16 MB (B,S,D f16)

  k_cast_f16<<<4096, 256, 0, stream>>>(src, srch);
  k_castT<<<dim3(16, 16, 3), 256, 0, stream>>>(Wq, Wk, Wv, wt);
  k_qkv3<<<dim3(32, 12), 512, 0, stream>>>(srch, wt, qp, kp, vp);
  k_scrT<<<dim3(32, 16, 4), 256, 0, stream>>>(vp, vtT);
  k_scores<<<dim3(8, 8, 4), 512, 0, stream>>>(qp, kp, abf);
  k_softmax<<<NROWS, 256, 0, stream>>>(Aout, abf);
  k_att<<<dim3(8, 8, 4), 512, 0, stream>>>(abf, vtT, attb);
  k_ln<<<NROWS, 256, 0, stream>>>(attb, src, l1w, l1b, l2w, l2b, Xout);
}

// Round 4
// 201.426 us; speedup vs baseline: 1.5103x; 1.0383x over previous
//
#include <hip/hip_runtime.h>

typedef _Float16 f16;
typedef __attribute__((ext_vector_type(2))) _Float16 f16x2;
typedef __attribute__((ext_vector_type(4))) _Float16 f16x4;
typedef __attribute__((ext_vector_type(8))) _Float16 f16x8;
typedef __attribute__((ext_vector_type(4))) float f32x4;

#define D_MODEL 1024
#define SEQ 2048
#define NBATCH 4
#define NROWS (NBATCH * SEQ)  // 8192

// ---------------------------------------------------------------- utilities
__device__ __forceinline__ void gload16(const void* g, void* l) {
  __builtin_amdgcn_global_load_lds(
      (__attribute__((address_space(1))) void*)(void*)g,
      (__attribute__((address_space(3))) void*)l, 16, 0, 0);
}

// barrier with compiler-only memory fences (no hardware waitcnt drain)
#define BARF                                   \
  do {                                         \
    asm volatile("" ::: "memory");             \
    __builtin_amdgcn_s_barrier();              \
    asm volatile("" ::: "memory");             \
  } while (0)
#define PRIO1 __builtin_amdgcn_s_setprio(1)
#define PRIO0 __builtin_amdgcn_s_setprio(0)

// ---------------------------------------------------------- 8-wave GEMM core
// BM=256, BN in {256,128}, BK=64, 512 threads (8 waves = 2M x 4N), f16 MFMA
// 16x16x32, fp32 acc. LDS double-buffered slots: A[256][64] + B[BN][64],
// XOR-swizzled via pre-swizzled global source (keyA=row&7, keyB=(row>>2)&7).
// 2 phases per K-tile, ONE barrier per phase, compiler-scheduled interleave:
//  p1: STAGE_A(kt+1 -> slot^1); read A-half0 + all B (slot); 32 MFMA; bar
//  p2: read A-half1; STAGE_B(kt+2 -> slot); vmcnt(LB); 32 MFMA; bar
// vmcnt(LB) = exactly the B loads just issued -> A(kt+1),B(kt+1) landed.
// Stages always sit >=1 barrier after the staged region's last read.
template <int BN>
__device__ __forceinline__ void gemm8_core(
    const f16* aP0, const f16* aP1, const f16* aP2, const f16* aP3,
    const f16* bP0, const f16* bP1, const f16* bP2, const f16* bP3,
    int stepA, int stepB, int NT, f16* lds, f32x4* acc)
{
  constexpr int NJ = BN / 128;           // n-frag pairs per n-half (2|1)
  constexpr int NACC = 2 * NJ;           // acc columns (4|2)
  constexpr int SLOT = 16384 + BN * 64;  // f16 units per slot
  const int t = threadIdx.x, l = t & 63;
  const int w = t >> 6, wm = w >> 2, wn = w & 3;
  const int fr = l & 15, g0 = l >> 4;

  // fragment LDS read offsets (f16 units within slot), swizzled
  int aof[2][4][2], bof[2][NJ][2];
#pragma unroll
  for (int mh = 0; mh < 2; ++mh)
#pragma unroll
    for (int mi = 0; mi < 4; ++mi)
#pragma unroll
      for (int kh = 0; kh < 2; ++kh) {
        const int ra = wm * 128 + mh * 64 + mi * 16 + fr;
        aof[mh][mi][kh] = ra * 64 + (((g0 + kh * 4) ^ (ra & 7)) << 3);
      }
#pragma unroll
  for (int nh = 0; nh < 2; ++nh)
#pragma unroll
    for (int j = 0; j < NJ; ++j)
#pragma unroll
      for (int kh = 0; kh < 2; ++kh) {
        const int rb = (BN == 256) ? (wn * 64 + fr * 4 + nh * 2 + j)
                                   : (wn * 32 + fr * 2 + nh);
        bof[nh][j][kh] = rb * 64 + (((g0 + kh * 4) ^ ((rb >> 2) & 7)) << 3);
      }
#pragma unroll
  for (int i = 0; i < 8 * NACC; ++i) acc[i] = f32x4{0.f, 0.f, 0.f, 0.f};

  f16x8 fa[4][2];      // A frags of current m-half
  f16x8 fb[2][NJ][2];  // all B frags of the K-tile

#define STAGE_A(SL)                                  \
  {                                                  \
    f16* d = lds + (SL) * SLOT + t * 8;              \
    gload16(aP0, d);                                 \
    gload16(aP1, d + 4096);                          \
    gload16(aP2, d + 8192);                          \
    gload16(aP3, d + 12288);                         \
  }
#define STAGE_B(SL)                                  \
  {                                                  \
    f16* d = lds + (SL) * SLOT + 16384 + t * 8;      \
    gload16(bP0, d);                                 \
    gload16(bP1, d + 4096);                          \
    if constexpr (BN == 256) {                       \
      gload16(bP2, d + 8192);                        \
      gload16(bP3, d + 12288);                       \
    }                                                \
  }
#define ADVA { aP0 += stepA; aP1 += stepA; aP2 += stepA; aP3 += stepA; }
#define ADVB                                         \
  {                                                  \
    bP0 += stepB; bP1 += stepB;                      \
    if constexpr (BN == 256) { bP2 += stepB; bP3 += stepB; } \
  }
#define VMC                                                        \
  if constexpr (BN == 256) {                                       \
    asm volatile("s_waitcnt vmcnt(4)" ::: "memory");               \
  } else {                                                         \
    asm volatile("s_waitcnt vmcnt(2)" ::: "memory");               \
  }
#define LOAD_A(MH)                                   \
  _Pragma("unroll") for (int mi = 0; mi < 4; ++mi)   \
  _Pragma("unroll") for (int kh = 0; kh < 2; ++kh)   \
      fa[mi][kh] = *(const f16x8*)(LA + aof[MH][mi][kh]);
#define LOAD_B(NH)                                   \
  _Pragma("unroll") for (int j = 0; j < NJ; ++j)     \
  _Pragma("unroll") for (int kh = 0; kh < 2; ++kh)   \
      fb[NH][j][kh] = *(const f16x8*)(LBp + bof[NH][j][kh]);
#define MFMA_BLK(MH, NH)                                                    \
  _Pragma("unroll") for (int mi = 0; mi < 4; ++mi)                          \
  _Pragma("unroll") for (int j = 0; j < NJ; ++j)                            \
  _Pragma("unroll") for (int kh = 0; kh < 2; ++kh)                          \
      acc[((MH)*4 + mi) * NACC + (NH)*NJ + j] =                             \
          __builtin_amdgcn_mfma_f32_16x16x32_f16(                           \
              fa[mi][kh], fb[NH][j][kh],                                    \
              acc[((MH)*4 + mi) * NACC + (NH)*NJ + j], 0, 0, 0);

  (void)bP2; (void)bP3;
  // prologue: A(0)->slot0, B(0)->slot0, B(1)->slot1; wait A0,B0 landed.
  STAGE_A(0); ADVA;              // aP -> tile 1
  STAGE_B(0); ADVB;
  STAGE_B(1); ADVB;              // bP -> tile 2
  VMC;                           // allow B(1) outstanding only
  BARF;

  for (int kt = 0; kt < NT; ++kt) {
    const int sl = kt & 1;
    const f16* LA = lds + sl * SLOT;
    const f16* LBp = LA + 16384;
    // ---- phase 1
    STAGE_A(sl ^ 1);             // tile kt+1's A (region last read kt-1.p2)
    if (kt + 2 < NT) ADVA;
    LOAD_A(0); LOAD_B(0); LOAD_B(1);
    PRIO1; MFMA_BLK(0, 0); MFMA_BLK(0, 1); PRIO0;
    BARF;
    // ---- phase 2
    LOAD_A(1);
    STAGE_B(sl);                 // tile kt+2's B (region last read kt.p1)
    if (kt + 3 < NT) ADVB;
    VMC;                         // A(kt+1), B(kt+1) landed; B(kt+2) in flight
    PRIO1; MFMA_BLK(1, 0); MFMA_BLK(1, 1); PRIO0;
    BARF;
  }
#undef STAGE_A
#undef STAGE_B
#undef ADVA
#undef ADVB
#undef VMC
#undef LOAD_A
#undef LOAD_B
#undef MFMA_BLK
}

// ------------------------------------------- GEMM1: QKV, BN=128, grid 32x24
__global__ __launch_bounds__(512, 2) void k_qkv3(
    const f16* __restrict__ srch, const f16* __restrict__ wt,
    f16* __restrict__ qp, f16* __restrict__ kp, f16* __restrict__ vp)
{
  __shared__ f16 lds[2 * (16384 + 128 * 64)];
  const int t = threadIdx.x, l = t & 63;
  const int w = t >> 6, wm = w >> 2, wn = w & 3;
  const int fr = l & 15, g0 = l >> 4, c = t & 7;
  const int z = blockIdx.y >> 3, cb = blockIdx.y & 7;
  const f16 *aP[4], *bP[2];
#pragma unroll
  for (int i = 0; i < 4; ++i) {
    const int rl = i * 64 + (t >> 3);
    aP[i] = srch + (size_t)(blockIdx.x * 256 + rl) * 1024 + ((c ^ (rl & 7)) << 3);
  }
#pragma unroll
  for (int i = 0; i < 2; ++i) {
    const int rl = i * 64 + (t >> 3);
    bP[i] = wt + ((size_t)z << 20) + (size_t)(cb * 128 + rl) * 1024 +
            ((c ^ ((rl >> 2) & 7)) << 3);
  }
  f32x4 acc[16];
  gemm8_core<128>(aP[0], aP[1], aP[2], aP[3], bP[0], bP[1], bP[0], bP[0],
                  64, 64, 16, lds, acc);
  f16* dst = (z == 0) ? qp : (z == 1 ? kp : vp);
  const int col = cb * 128 + wn * 32 + fr * 2;
#pragma unroll
  for (int mi = 0; mi < 8; ++mi)
#pragma unroll
    for (int q = 0; q < 4; ++q) {
      const int row = blockIdx.x * 256 + wm * 128 + mi * 16 + g0 * 4 + q;
      f16x2 o = {(f16)acc[mi * 2 + 0][q], (f16)acc[mi * 2 + 1][q]};
      *(f16x2*)(dst + (size_t)row * 1024 + col) = o;
    }
}

// --------------------------- GEMM2: scores = Qt*Kt^T/32, f16 out (gathered)
__global__ __launch_bounds__(512, 2) void k_scores(
    const f16* __restrict__ qp, const f16* __restrict__ kp,
    f16* __restrict__ abf)
{
  __shared__ f16 lds[2 * (16384 + 256 * 64)];
  const int t = threadIdx.x, l = t & 63;
  const int w = t >> 6, wm = w >> 2, wn = w & 3;
  const int fr = l & 15, g0 = l >> 4, c = t & 7;
  const int b = blockIdx.z;
  const f16* qb = qp + ((size_t)b << 21);
  const f16* kb = kp + ((size_t)b << 21);
  const f16 *aP[4], *bP[4];
#pragma unroll
  for (int i = 0; i < 4; ++i) {
    const int rl = i * 64 + (t >> 3);
    const int spA = blockIdx.x * 256 + rl;
    aP[i] = qb + (size_t)((spA & 127) << 4) * 1024 + ((spA >> 7) << 6) +
            ((c ^ (rl & 7)) << 3);
    const int spB = blockIdx.y * 256 + rl;
    bP[i] = kb + (size_t)((spB & 127) << 4) * 1024 + ((spB >> 7) << 6) +
            ((c ^ ((rl >> 2) & 7)) << 3);
  }
  f32x4 acc[32];
  gemm8_core<256>(aP[0], aP[1], aP[2], aP[3], bP[0], bP[1], bP[2], bP[3],
                  1024, 1024, 16, lds, acc);
  f16* Cb = abf + ((size_t)b << 22);
  const int col = blockIdx.y * 256 + wn * 64 + fr * 4;
#pragma unroll
  for (int mi = 0; mi < 8; ++mi)
#pragma unroll
    for (int q = 0; q < 4; ++q) {
      const int row = blockIdx.x * 256 + wm * 128 + mi * 16 + g0 * 4 + q;
      f16x4 o = {(f16)(acc[mi * 4 + 0][q] * 0.03125f),
                 (f16)(acc[mi * 4 + 1][q] * 0.03125f),
                 (f16)(acc[mi * 4 + 2][q] * 0.03125f),
                 (f16)(acc[mi * 4 + 3][q] * 0.03125f)};
      *(f16x4*)(Cb + (size_t)row * 2048 + col) = o;
    }
}

// ------------------------------------- GEMM3: att = a * Vt, f16 out, BN=128
__global__ __launch_bounds__(512, 2) void k_att(
    const f16* __restrict__ abf, const f16* __restrict__ vtT,
    f16* __restrict__ attb)
{
  __shared__ f16 lds[2 * (16384 + 128 * 64)];
  const int t = threadIdx.x, l = t & 63;
  const int w = t >> 6, wm = w >> 2, wn = w & 3;
  const int fr = l & 15, g0 = l >> 4, c = t & 7;
  const int b = blockIdx.z;
  const f16* ab = abf + ((size_t)b << 22);
  const f16* vb = vtT + ((size_t)b << 21);
  const f16 *aP[4], *bP[2];
#pragma unroll
  for (int i = 0; i < 4; ++i) {
    const int rl = i * 64 + (t >> 3);
    aP[i] = ab + (size_t)(blockIdx.x * 256 + rl) * 2048 + ((c ^ (rl & 7)) << 3);
  }
#pragma unroll
  for (int i = 0; i < 2; ++i) {
    const int rl = i * 64 + (t >> 3);
    bP[i] = vb + (size_t)(blockIdx.y * 128 + rl) * 2048 +
            ((c ^ ((rl >> 2) & 7)) << 3);
  }
  f32x4 acc[16];
  gemm8_core<128>(aP[0], aP[1], aP[2], aP[3], bP[0], bP[1], bP[0], bP[0],
                  64, 64, 32, lds, acc);
  f16* Cb = attb + ((size_t)b << 21);
  const int col = blockIdx.y * 128 + wn * 32 + fr * 2;
#pragma unroll
  for (int mi = 0; mi < 8; ++mi)
#pragma unroll
    for (int q = 0; q < 4; ++q) {
      const int row = blockIdx.x * 256 + wm * 128 + mi * 16 + g0 * 4 + q;
      f16x2 o = {(f16)acc[mi * 2 + 0][q], (f16)acc[mi * 2 + 1][q]};
      *(f16x2*)(Cb + (size_t)row * 1024 + col) = o;
    }
}

// ------------------------------------------- scramble-transpose of V
__global__ __launch_bounds__(256) void k_scrT(const f16* __restrict__ vp,
                                              f16* __restrict__ vtT)
{
  __shared__ f16 tile[64][68];
  const int t = threadIdx.x;
  const int sp0 = blockIdx.x * 64, dp0 = blockIdx.y * 64;
  const int d6 = dp0 >> 6;
  const int jb = (sp0 >> 7) << 6;
  const int sbase = sp0 & 127;
  const f16* src = vp + ((size_t)blockIdx.z << 21);
  f16* dst = vtT + ((size_t)blockIdx.z << 21);
#pragma unroll
  for (int p = 0; p < 2; ++p) {
    const int u = p * 32 + (t >> 3);
    const int s = ((sbase + u) << 4) | d6;
    const int c = (t & 7) << 3;
    f16x8 v = *(const f16x8*)(src + (size_t)s * 1024 + jb + c);
    *(f16x4*)&tile[u][c]     = f16x4{v[0], v[1], v[2], v[3]};
    *(f16x4*)&tile[u][c + 4] = f16x4{v[4], v[5], v[6], v[7]};
  }
  __syncthreads();
#pragma unroll
  for (int p = 0; p < 2; ++p) {
    const int cc = p * 32 + (t >> 3);
    const int v0 = (t & 7) << 3;
    f16x8 o;
#pragma unroll
    for (int j = 0; j < 8; ++j) o[j] = tile[v0 + j][cc];
    *(f16x8*)(dst + (size_t)(dp0 + cc) * 2048 + sp0 + v0) = o;
  }
}

// -------------------------------------------------------------- casts
__global__ __launch_bounds__(256) void k_cast_f16(const float* __restrict__ in,
                                                  f16* __restrict__ out)
{
  const size_t i = (size_t)blockIdx.x * 256 + threadIdx.x;
  const float4* p = (const float4*)in;
  float4 v0 = p[2 * i], v1 = p[2 * i + 1];
  f16x8 o;
  o[0] = (f16)v0.x; o[1] = (f16)v0.y; o[2] = (f16)v0.z; o[3] = (f16)v0.w;
  o[4] = (f16)v1.x; o[5] = (f16)v1.y; o[6] = (f16)v1.z; o[7] = (f16)v1.w;
  *(f16x8*)(out + 8 * i) = o;
}

__global__ __launch_bounds__(256) void k_castT(
    const float* __restrict__ w0, const float* __restrict__ w1,
    const float* __restrict__ w2, f16* __restrict__ out)
{
  const float* in = (blockIdx.z == 0) ? w0 : (blockIdx.z == 1 ? w1 : w2);
  f16* o = out + ((size_t)blockIdx.z << 20);
  __shared__ f16 tile[64][65];
  const int t = threadIdx.x;
  const int rr = t >> 4, c4 = (t & 15) * 4;
  const int r0 = blockIdx.x * 64, c0 = blockIdx.y * 64;
#pragma unroll
  for (int i = 0; i < 4; ++i) {
    float4 f = *(const float4*)(in + (size_t)(r0 + rr + 16 * i) * 1024 + c0 + c4);
    tile[rr + 16 * i][c4 + 0] = (f16)f.x;
    tile[rr + 16 * i][c4 + 1] = (f16)f.y;
    tile[rr + 16 * i][c4 + 2] = (f16)f.z;
    tile[rr + 16 * i][c4 + 3] = (f16)f.w;
  }
  __syncthreads();
#pragma unroll
  for (int i = 0; i < 4; ++i) {
    const int n = c0 + rr + 16 * i;
    f16* dst = o + (size_t)n * 1024 + r0 + c4;
    dst[0] = tile[c4 + 0][rr + 16 * i];
    dst[1] = tile[c4 + 1][rr + 16 * i];
    dst[2] = tile[c4 + 2][rr + 16 * i];
    dst[3] = tile[c4 + 3][rr + 16 * i];
  }
}

// ------------------- softmax: reads f16 scores, writes f32 a + f16 in place
__global__ __launch_bounds__(256) void k_softmax(float* __restrict__ out,
                                                 f16* __restrict__ abf)
{
  const size_t base = (size_t)blockIdx.x * 2048;
  const int t = threadIdx.x, lane = t & 63, w = t >> 6;
  f16x8 v = *(const f16x8*)(abf + base + (size_t)t * 8);
  float x[8];
#pragma unroll
  for (int j = 0; j < 8; ++j) x[j] = (float)v[j];
  float m = fmaxf(fmaxf(fmaxf(x[0], x[1]), fmaxf(x[2], x[3])),
                  fmaxf(fmaxf(x[4], x[5]), fmaxf(x[6], x[7])));
#pragma unroll
  for (int off = 1; off < 64; off <<= 1) m = fmaxf(m, __shfl_xor(m, off));
  __shared__ float red[8];
  if (lane == 0) red[w] = m;
  __syncthreads();
  m = fmaxf(fmaxf(red[0], red[1]), fmaxf(red[2], red[3]));
  float s = 0.f;
#pragma unroll
  for (int j = 0; j < 8; ++j) { x[j] = __expf(x[j] - m); s += x[j]; }
#pragma unroll
  for (int off = 1; off < 64; off <<= 1) s += __shfl_xor(s, off);
  if (lane == 0) red[4 + w] = s;
  __syncthreads();
  s = red[4] + red[5] + red[6] + red[7];
  const float inv = 1.0f / s;
#pragma unroll
  for (int j = 0; j < 8; ++j) x[j] *= inv;
  float4 o0 = {x[0], x[1], x[2], x[3]}, o1 = {x[4], x[5], x[6], x[7]};
  ((float4*)(out + base))[2 * t] = o0;
  ((float4*)(out + base))[2 * t + 1] = o1;
  f16x8 ov;
#pragma unroll
  for (int j = 0; j < 8; ++j) ov[j] = (f16)x[j];
  *(f16x8*)(abf + base + (size_t)t * 8) = ov;
}

// --------------------------------------------- fused LN1 + add + LN2
__global__ __launch_bounds__(256) void k_ln(
    const f16* __restrict__ attb, const float* __restrict__ src,
    const float* __restrict__ w1, const float* __restrict__ b1,
    const float* __restrict__ w2, const float* __restrict__ b2,
    float* __restrict__ out)
{
  const size_t base = (size_t)blockIdx.x * 1024;
  const int t = threadIdx.x, lane = t & 63, w = t >> 6;
  f16x4 a4 = ((const f16x4*)(attb + base))[t];
  float ax = (float)a4[0], ay = (float)a4[1], az = (float)a4[2], aw = (float)a4[3];
  float s = ax + ay + az + aw;
  float s2 = ax * ax + ay * ay + az * az + aw * aw;
#pragma unroll
  for (int off = 1; off < 64; off <<= 1) {
    s += __shfl_xor(s, off);
    s2 += __shfl_xor(s2, off);
  }
  __shared__ float red[16];
  if (lane == 0) { red[w] = s; red[4 + w] = s2; }
  __syncthreads();
  s = red[0] + red[1] + red[2] + red[3];
  s2 = red[4] + red[5] + red[6] + red[7];
  float mu = s * (1.0f / 1024.0f);
  float var = s2 * (1.0f / 1024.0f) - mu * mu;
  float rs = rsqrtf(var + 1e-5f);
  float4 W1 = ((const float4*)w1)[t], B1 = ((const float4*)b1)[t];
  float4 sv = ((const float4*)(src + base))[t];
  float y0 = sv.x + (ax - mu) * rs * W1.x + B1.x;
  float y1 = sv.y + (ay - mu) * rs * W1.y + B1.y;
  float y2 = sv.z + (az - mu) * rs * W1.z + B1.z;
  float y3 = sv.w + (aw - mu) * rs * W1.w + B1.w;
  s = y0 + y1 + y2 + y3;
  s2 = y0 * y0 + y1 * y1 + y2 * y2 + y3 * y3;
#pragma unroll
  for (int off = 1; off < 64; off <<= 1) {
    s += __shfl_xor(s, off);
    s2 += __shfl_xor(s2, off);
  }
  if (lane == 0) { red[8 + w] = s; red[12 + w] = s2; }
  __syncthreads();
  s = red[8] + red[9] + red[10] + red[11];
  s2 = red[12] + red[13] + red[14] + red[15];
  mu = s * (1.0f / 1024.0f);
  var = s2 * (1.0f / 1024.0f) - mu * mu;
  rs = rsqrtf(var + 1e-5f);
  float4 W2 = ((const float4*)w2)[t], B2 = ((const float4*)b2)[t];
  float4 o;
  o.x = (y0 - mu) * rs * W2.x + B2.x;
  o.y = (y1 - mu) * rs * W2.y + B2.y;
  o.z = (y2 - mu) * rs * W2.z + B2.z;
  o.w = (y3 - mu) * rs * W2.w + B2.w;
  ((float4*)(out + base))[t] = o;
}

// ---------------------------------------------------------------- launch
extern "C" void kernel_launch(void* const* d_in, const int* in_sizes, int n_in,
                              void* d_out, int out_size, void* d_ws, size_t ws_size,
                              hipStream_t stream) {
  const float* src = (const float*)d_in[0];
  const float* Wq  = (const float*)d_in[1];
  const float* Wk  = (const float*)d_in[2];
  const float* Wv  = (const float*)d_in[3];
  const float* l1w = (const float*)d_in[4];
  const float* l1b = (const float*)d_in[5];
  const float* l2w = (const float*)d_in[6];
  const float* l2b = (const float*)d_in[7];
  float* Xout = (float*)d_out;
  float* Aout = Xout + (size_t)NROWS * D_MODEL;

  // workspace layout (134 MB, non-overlapping)
  char* ws = (char*)d_ws;
  f16* srch = (f16*)ws;                       // 16 MB (8192x1024)
  f16* wt   = (f16*)(ws + (16u << 20));       //  6 MB (3072x1024, W^T)
  f16* qp   = (f16*)(ws + (22u << 20));       // 16 MB
  f16* kp   = (f16*)(ws + (38u << 20));       // 16 MB
  f16* vp   = (f16*)(ws + (54u << 20));       // 16 MB
  f16* vtT  = (f16*)(ws + (70u << 20));       // 16 MB (B,D,S scrambled-T)
  f16* abf  = (f16*)(ws + (86u << 20));       // 32 MB (B,S,S scores->a f16)
  f16* attb = (f16*)(ws + (118u << 20));      // 16 MB (B,S,D f16)

  k_cast_f16<<<4096, 256, 0, stream>>>(src, srch);
  k_castT<<<dim3(16, 16, 3), 256, 0, stream>>>(Wq, Wk, Wv, wt);
  k_qkv3<<<dim3(32, 24), 512, 0, stream>>>(srch, wt, qp, kp, vp);
  k_scrT<<<dim3(32, 16, 4), 256, 0, stream>>>(vp, vtT);
  k_scores<<<dim3(8, 8, 4), 512, 0, stream>>>(qp, kp, abf);
  k_softmax<<<NROWS, 256, 0, stream>>>(Aout, abf);
  k_att<<<dim3(8, 8, 4), 512, 0, stream>>>(abf, vtT, attb);
  k_ln<<<NROWS, 256, 0, stream>>>(attb, src, l1w, l1b, l2w, l2b, Xout);
}

// Round 5
// 199.783 us; speedup vs baseline: 1.5227x; 1.0082x over previous
//
#include <hip/hip_runtime.h>

typedef _Float16 f16;
typedef __attribute__((ext_vector_type(2))) _Float16 f16x2;
typedef __attribute__((ext_vector_type(4))) _Float16 f16x4;
typedef __attribute__((ext_vector_type(8))) _Float16 f16x8;
typedef __attribute__((ext_vector_type(4))) float f32x4;

#define D_MODEL 1024
#define SEQ 2048
#define NBATCH 4
#define NROWS (NBATCH * SEQ)  // 8192

// ---------------------------------------------------------------- utilities
__device__ __forceinline__ void gload16(const void* g, void* l) {
  __builtin_amdgcn_global_load_lds(
      (__attribute__((address_space(1))) void*)(void*)g,
      (__attribute__((address_space(3))) void*)l, 16, 0, 0);
}

#define BARF                                   \
  do {                                         \
    asm volatile("" ::: "memory");             \
    __builtin_amdgcn_s_barrier();              \
    asm volatile("" ::: "memory");             \
  } while (0)
#define LGK asm volatile("s_waitcnt lgkmcnt(0)" ::: "memory")
#define PRIO1 __builtin_amdgcn_s_setprio(1)
#define PRIO0 __builtin_amdgcn_s_setprio(0)

// ------------------------------------------------------- 8-phase GEMM core
// BM=256, BN in {256,128}, BK=64, 512 threads (8 waves = 2M x 4N), f16 MFMA
// 16x16x32, fp32 acc. LDS (f16 units):
//   A slots (d,h): (d*2+h)*8192   d=dbuf, h=row-half (128x64 each)
//   B slots: BN=256: 32768+(d*2+h)*8192 ; BN=128: 32768+d*8192
// Per 2-K-tile iteration: 8 phases, each = {ds_reads; stage half-tile;
// [vmcnt @P4/P8]; barrier; lgkmcnt(0); setprio1; MFMA quadrant; setprio0;
// barrier}. Stage rotation (T0=2i,T1=2i+1,T2,T3 ahead):
//   P1:T1.A0 P2:T1.A1 P3:T2.B0 P4:T2.B1 P5:T2.A0 P6:T2.A1 P7:T3.B0 P8:T3.B1
// (BN=128: B single-half, staged at P3/P7 only.)
// WAR: each stage >=1 barrier after its LDS region's last ds_read.
// vmcnt(4|2) at P4 ensures T1 fully landed before P5's reads; at P8 ensures
// T2 landed before next-P1. Never vmcnt(0) in-loop.

#define STAGE_A(D, H)                                        \
  {                                                          \
    f16* d_ = lds + ((D) * 2 + (H)) * 8192 + t * 8;          \
    gload16((H) ? aP2 : aP0, d_);                            \
    gload16((H) ? aP3 : aP1, d_ + 4096);                     \
  }
#define STAGE_B(D, H)                                        \
  {                                                          \
    if constexpr (BN == 256) {                               \
      f16* d_ = lds + 32768 + ((D) * 2 + (H)) * 8192 + t * 8;\
      gload16((H) ? bP2 : bP0, d_);                          \
      gload16((H) ? bP3 : bP1, d_ + 4096);                   \
    } else {                                                 \
      f16* d_ = lds + 32768 + (D) * 8192 + t * 8;            \
      gload16(bP0, d_);                                      \
      gload16(bP1, d_ + 4096);                               \
    }                                                        \
  }
#define ADVA                                                 \
  {                                                          \
    if (ka < NT - 1) {                                       \
      ka++;                                                  \
      aP0 += stepA; aP1 += stepA; aP2 += stepA; aP3 += stepA;\
    }                                                        \
  }
#define ADVB                                                 \
  {                                                          \
    if (kb < NT - 1) {                                       \
      kb++;                                                  \
      bP0 += stepB; bP1 += stepB;                            \
      if constexpr (BN == 256) { bP2 += stepB; bP3 += stepB; } \
    }                                                        \
  }
#define VMC_STEADY                                           \
  {                                                          \
    if constexpr (BN == 256) {                               \
      asm volatile("s_waitcnt vmcnt(4)" ::: "memory");       \
    } else {                                                 \
      asm volatile("s_waitcnt vmcnt(2)" ::: "memory");       \
    }                                                        \
  }
#define RD_A(D, MH)                                          \
  _Pragma("unroll") for (int mi = 0; mi < 4; ++mi)           \
  _Pragma("unroll") for (int kh = 0; kh < 2; ++kh) {         \
    const int rr = (MH) * 64 + mi * 16 + fr;                 \
    fa[mi][kh] = *(const f16x8*)(lds + ((D) * 2 + wm) * 8192 \
        + rr * 64 + (((g0 + kh * 4) ^ (rr & 7)) << 3));      \
  }
#define RD_B(D, NH)                                          \
  _Pragma("unroll") for (int j = 0; j < NJ; ++j)             \
  _Pragma("unroll") for (int kh = 0; kh < 2; ++kh) {         \
    int rbr, base;                                           \
    if constexpr (BN == 256) {                               \
      rbr = (wn & 1) * 64 + fr * 4 + (NH) * 2 + j;           \
      base = 32768 + ((D) * 2 + (wn >> 1)) * 8192;           \
    } else {                                                 \
      rbr = wn * 32 + fr * 2 + (NH);                         \
      base = 32768 + (D) * 8192;                             \
    }                                                        \
    fb[NH][j][kh] = *(const f16x8*)(lds + base + rbr * 64 +  \
        (((g0 + kh * 4) ^ ((rbr >> 2) & 7)) << 3));          \
  }
#define MFMA_Q(MH, NH)                                       \
  _Pragma("unroll") for (int mi = 0; mi < 4; ++mi)           \
  _Pragma("unroll") for (int j = 0; j < NJ; ++j)             \
  _Pragma("unroll") for (int kh = 0; kh < 2; ++kh)           \
    acc[((MH) * 4 + mi) * 2 * NJ + (NH) * NJ + j] =          \
        __builtin_amdgcn_mfma_f32_16x16x32_f16(              \
            fa[mi][kh], fb[NH][j][kh],                       \
            acc[((MH) * 4 + mi) * 2 * NJ + (NH) * NJ + j], 0, 0, 0);

template <int BN>
__device__ __forceinline__ void gemm8p(
    const f16* aP0, const f16* aP1, const f16* aP2, const f16* aP3,
    const f16* bP0, const f16* bP1, const f16* bP2, const f16* bP3,
    int stepA, int stepB, int NT, f16* lds, f32x4* acc)
{
  constexpr int NJ = BN / 128;
  const int t = threadIdx.x, l = t & 63;
  const int w = t >> 6, wm = w >> 2, wn = w & 3;
  const int fr = l & 15, g0 = l >> 4;
  f16x8 fa[4][2], fb[2][NJ][2];
#pragma unroll
  for (int i = 0; i < 8 * 2 * NJ; ++i) acc[i] = f32x4{0.f, 0.f, 0.f, 0.f};
  int ka = 0, kb = 0;
  (void)bP2; (void)bP3;

  // prologue: T0.A -> dbuf0, T0.B -> dbuf0, T1.B -> dbuf1
  STAGE_A(0, 0); STAGE_A(0, 1); ADVA;
  if constexpr (BN == 256) { STAGE_B(0, 0); STAGE_B(0, 1); }
  else { STAGE_B(0, 0); }
  ADVB;
  if constexpr (BN == 256) { STAGE_B(1, 0); STAGE_B(1, 1); }
  else { STAGE_B(1, 0); }
  ADVB;
  VMC_STEADY;   // T0 fully landed; T1.B in flight
  BARF;

#pragma unroll 1
  for (int it = 0; it < NT / 2; ++it) {
    // ---- P1: T0 quadrant (0,0); stage T1.A0
    RD_A(0, 0); RD_B(0, 0);
    STAGE_A(1, 0);
    BARF; LGK;
    PRIO1; MFMA_Q(0, 0); PRIO0;
    BARF;
    // ---- P2: (0,1); stage T1.A1
    RD_B(0, 1);
    STAGE_A(1, 1); ADVA;
    BARF; LGK;
    PRIO1; MFMA_Q(0, 1); PRIO0;
    BARF;
    // ---- P3: (1,0); stage T2.B0
    RD_A(0, 1);
    STAGE_B(0, 0);
    if constexpr (BN == 128) ADVB;
    BARF; LGK;
    PRIO1; MFMA_Q(1, 0); PRIO0;
    BARF;
    // ---- P4: (1,1); stage T2.B1; counted vmcnt -> T1 landed
    if constexpr (BN == 256) { STAGE_B(0, 1); ADVB; }
    VMC_STEADY;
    BARF;
    PRIO1; MFMA_Q(1, 1); PRIO0;
    BARF;
    // ---- P5: T1 quadrant (0,0); stage T2.A0
    RD_A(1, 0); RD_B(1, 0);
    STAGE_A(0, 0);
    BARF; LGK;
    PRIO1; MFMA_Q(0, 0); PRIO0;
    BARF;
    // ---- P6: (0,1); stage T2.A1
    RD_B(1, 1);
    STAGE_A(0, 1); ADVA;
    BARF; LGK;
    PRIO1; MFMA_Q(0, 1); PRIO0;
    BARF;
    // ---- P7: (1,0); stage T3.B0
    RD_A(1, 1);
    STAGE_B(1, 0);
    if constexpr (BN == 128) ADVB;
    BARF; LGK;
    PRIO1; MFMA_Q(1, 0); PRIO0;
    BARF;
    // ---- P8: (1,1); stage T3.B1; counted vmcnt -> T2 landed
    if constexpr (BN == 256) { STAGE_B(1, 1); ADVB; }
    VMC_STEADY;
    BARF;
    PRIO1; MFMA_Q(1, 1); PRIO0;
    BARF;
  }
}

// ------------------------------------------- GEMM1: QKV, BN=128, grid 32x24
__global__ __launch_bounds__(512, 2) void k_qkv3(
    const f16* __restrict__ srch, const f16* __restrict__ wt,
    f16* __restrict__ qp, f16* __restrict__ kp, f16* __restrict__ vp)
{
  __shared__ f16 lds[49152];
  const int t = threadIdx.x, l = t & 63;
  const int w = t >> 6, wm = w >> 2, wn = w & 3;
  const int fr = l & 15, g0 = l >> 4, c = t & 7;
  const int z = blockIdx.y >> 3, cb = blockIdx.y & 7;
  const f16 *aP[4], *bP[2];
#pragma unroll
  for (int i = 0; i < 4; ++i) {
    const int rl = i * 64 + (t >> 3);
    aP[i] = srch + (size_t)(blockIdx.x * 256 + rl) * 1024 + ((c ^ (rl & 7)) << 3);
  }
#pragma unroll
  for (int i = 0; i < 2; ++i) {
    const int rl = i * 64 + (t >> 3);
    bP[i] = wt + ((size_t)z << 20) + (size_t)(cb * 128 + rl) * 1024 +
            ((c ^ ((rl >> 2) & 7)) << 3);
  }
  f32x4 acc[16];
  gemm8p<128>(aP[0], aP[1], aP[2], aP[3], bP[0], bP[1], bP[0], bP[0],
              64, 64, 16, lds, acc);
  f16* dst = (z == 0) ? qp : (z == 1 ? kp : vp);
  const int col = cb * 128 + wn * 32 + fr * 2;
#pragma unroll
  for (int mi = 0; mi < 8; ++mi)
#pragma unroll
    for (int q = 0; q < 4; ++q) {
      const int row = blockIdx.x * 256 + wm * 128 + mi * 16 + g0 * 4 + q;
      f16x2 o = {(f16)acc[mi * 2 + 0][q], (f16)acc[mi * 2 + 1][q]};
      *(f16x2*)(dst + (size_t)row * 1024 + col) = o;
    }
}

// --------------------------- GEMM2: scores = Qt*Kt^T/32, f16 out (gathered)
__global__ __launch_bounds__(512, 2) void k_scores(
    const f16* __restrict__ qp, const f16* __restrict__ kp,
    f16* __restrict__ abf)
{
  __shared__ f16 lds[65536];
  const int t = threadIdx.x, l = t & 63;
  const int w = t >> 6, wm = w >> 2, wn = w & 3;
  const int fr = l & 15, g0 = l >> 4, c = t & 7;
  const int b = blockIdx.z;
  const f16* qb = qp + ((size_t)b << 21);
  const f16* kb = kp + ((size_t)b << 21);
  const f16 *aP[4], *bP[4];
#pragma unroll
  for (int i = 0; i < 4; ++i) {
    const int rl = i * 64 + (t >> 3);
    const int spA = blockIdx.x * 256 + rl;
    aP[i] = qb + (size_t)((spA & 127) << 4) * 1024 + ((spA >> 7) << 6) +
            ((c ^ (rl & 7)) << 3);
    const int spB = blockIdx.y * 256 + rl;
    bP[i] = kb + (size_t)((spB & 127) << 4) * 1024 + ((spB >> 7) << 6) +
            ((c ^ ((rl >> 2) & 7)) << 3);
  }
  f32x4 acc[32];
  gemm8p<256>(aP[0], aP[1], aP[2], aP[3], bP[0], bP[1], bP[2], bP[3],
              1024, 1024, 16, lds, acc);
  f16* Cb = abf + ((size_t)b << 22);
  const int col = blockIdx.y * 256 + wn * 64 + fr * 4;
#pragma unroll
  for (int mi = 0; mi < 8; ++mi)
#pragma unroll
    for (int q = 0; q < 4; ++q) {
      const int row = blockIdx.x * 256 + wm * 128 + mi * 16 + g0 * 4 + q;
      f16x4 o = {(f16)(acc[mi * 4 + 0][q] * 0.03125f),
                 (f16)(acc[mi * 4 + 1][q] * 0.03125f),
                 (f16)(acc[mi * 4 + 2][q] * 0.03125f),
                 (f16)(acc[mi * 4 + 3][q] * 0.03125f)};
      *(f16x4*)(Cb + (size_t)row * 2048 + col) = o;
    }
}

// ------------------------------------- GEMM3: att = a * Vt, f16 out, BN=128
__global__ __launch_bounds__(512, 2) void k_att(
    const f16* __restrict__ abf, const f16* __restrict__ vtT,
    f16* __restrict__ attb)
{
  __shared__ f16 lds[49152];
  const int t = threadIdx.x, l = t & 63;
  const int w = t >> 6, wm = w >> 2, wn = w & 3;
  const int fr = l & 15, g0 = l >> 4, c = t & 7;
  const int b = blockIdx.z;
  const f16* ab = abf + ((size_t)b << 22);
  const f16* vb = vtT + ((size_t)b << 21);
  const f16 *aP[4], *bP[2];
#pragma unroll
  for (int i = 0; i < 4; ++i) {
    const int rl = i * 64 + (t >> 3);
    aP[i] = ab + (size_t)(blockIdx.x * 256 + rl) * 2048 + ((c ^ (rl & 7)) << 3);
  }
#pragma unroll
  for (int i = 0; i < 2; ++i) {
    const int rl = i * 64 + (t >> 3);
    bP[i] = vb + (size_t)(blockIdx.y * 128 + rl) * 2048 +
            ((c ^ ((rl >> 2) & 7)) << 3);
  }
  f32x4 acc[16];
  gemm8p<128>(aP[0], aP[1], aP[2], aP[3], bP[0], bP[1], bP[0], bP[0],
              64, 64, 32, lds, acc);
  f16* Cb = attb + ((size_t)b << 21);
  const int col = blockIdx.y * 128 + wn * 32 + fr * 2;
#pragma unroll
  for (int mi = 0; mi < 8; ++mi)
#pragma unroll
    for (int q = 0; q < 4; ++q) {
      const int row = blockIdx.x * 256 + wm * 128 + mi * 16 + g0 * 4 + q;
      f16x2 o = {(f16)acc[mi * 2 + 0][q], (f16)acc[mi * 2 + 1][q]};
      *(f16x2*)(Cb + (size_t)row * 1024 + col) = o;
    }
}

// ------------------------------------------- scramble-transpose of V
__global__ __launch_bounds__(256) void k_scrT(const f16* __restrict__ vp,
                                              f16* __restrict__ vtT)
{
  __shared__ f16 tile[64][68];
  const int t = threadIdx.x;
  const int sp0 = blockIdx.x * 64, dp0 = blockIdx.y * 64;
  const int d6 = dp0 >> 6;
  const int jb = (sp0 >> 7) << 6;
  const int sbase = sp0 & 127;
  const f16* src = vp + ((size_t)blockIdx.z << 21);
  f16* dst = vtT + ((size_t)blockIdx.z << 21);
#pragma unroll
  for (int p = 0; p < 2; ++p) {
    const int u = p * 32 + (t >> 3);
    const int s = ((sbase + u) << 4) | d6;
    const int c = (t & 7) << 3;
    f16x8 v = *(const f16x8*)(src + (size_t)s * 1024 + jb + c);
    *(f16x4*)&tile[u][c]     = f16x4{v[0], v[1], v[2], v[3]};
    *(f16x4*)&tile[u][c + 4] = f16x4{v[4], v[5], v[6], v[7]};
  }
  __syncthreads();
#pragma unroll
  for (int p = 0; p < 2; ++p) {
    const int cc = p * 32 + (t >> 3);
    const int v0 = (t & 7) << 3;
    f16x8 o;
#pragma unroll
    for (int j = 0; j < 8; ++j) o[j] = tile[v0 + j][cc];
    *(f16x8*)(dst + (size_t)(dp0 + cc) * 2048 + sp0 + v0) = o;
  }
}

// -------------------------------------------------------------- casts
__global__ __launch_bounds__(256) void k_cast_f16(const float* __restrict__ in,
                                                  f16* __restrict__ out)
{
  const size_t i = (size_t)blockIdx.x * 256 + threadIdx.x;
  const float4* p = (const float4*)in;
  float4 v0 = p[2 * i], v1 = p[2 * i + 1];
  f16x8 o;
  o[0] = (f16)v0.x; o[1] = (f16)v0.y; o[2] = (f16)v0.z; o[3] = (f16)v0.w;
  o[4] = (f16)v1.x; o[5] = (f16)v1.y; o[6] = (f16)v1.z; o[7] = (f16)v1.w;
  *(f16x8*)(out + 8 * i) = o;
}

__global__ __launch_bounds__(256) void k_castT(
    const float* __restrict__ w0, const float* __restrict__ w1,
    const float* __restrict__ w2, f16* __restrict__ out)
{
  const float* in = (blockIdx.z == 0) ? w0 : (blockIdx.z == 1 ? w1 : w2);
  f16* o = out + ((size_t)blockIdx.z << 20);
  __shared__ f16 tile[64][65];
  const int t = threadIdx.x;
  const int rr = t >> 4, c4 = (t & 15) * 4;
  const int r0 = blockIdx.x * 64, c0 = blockIdx.y * 64;
#pragma unroll
  for (int i = 0; i < 4; ++i) {
    float4 f = *(const float4*)(in + (size_t)(r0 + rr + 16 * i) * 1024 + c0 + c4);
    tile[rr + 16 * i][c4 + 0] = (f16)f.x;
    tile[rr + 16 * i][c4 + 1] = (f16)f.y;
    tile[rr + 16 * i][c4 + 2] = (f16)f.z;
    tile[rr + 16 * i][c4 + 3] = (f16)f.w;
  }
  __syncthreads();
#pragma unroll
  for (int i = 0; i < 4; ++i) {
    const int n = c0 + rr + 16 * i;
    f16* dst = o + (size_t)n * 1024 + r0 + c4;
    dst[0] = tile[c4 + 0][rr + 16 * i];
    dst[1] = tile[c4 + 1][rr + 16 * i];
    dst[2] = tile[c4 + 2][rr + 16 * i];
    dst[3] = tile[c4 + 3][rr + 16 * i];
  }
}

// ------------------- softmax: reads f16 scores, writes f32 a + f16 in place
__global__ __launch_bounds__(256) void k_softmax(float* __restrict__ out,
                                                 f16* __restrict__ abf)
{
  const size_t base = (size_t)blockIdx.x * 2048;
  const int t = threadIdx.x, lane = t & 63, w = t >> 6;
  f16x8 v = *(const f16x8*)(abf + base + (size_t)t * 8);
  float x[8];
#pragma unroll
  for (int j = 0; j < 8; ++j) x[j] = (float)v[j];
  float m = fmaxf(fmaxf(fmaxf(x[0], x[1]), fmaxf(x[2], x[3])),
                  fmaxf(fmaxf(x[4], x[5]), fmaxf(x[6], x[7])));
#pragma unroll
  for (int off = 1; off < 64; off <<= 1) m = fmaxf(m, __shfl_xor(m, off));
  __shared__ float red[8];
  if (lane == 0) red[w] = m;
  __syncthreads();
  m = fmaxf(fmaxf(red[0], red[1]), fmaxf(red[2], red[3]));
  float s = 0.f;
#pragma unroll
  for (int j = 0; j < 8; ++j) { x[j] = __expf(x[j] - m); s += x[j]; }
#pragma unroll
  for (int off = 1; off < 64; off <<= 1) s += __shfl_xor(s, off);
  if (lane == 0) red[4 + w] = s;
  __syncthreads();
  s = red[4] + red[5] + red[6] + red[7];
  const float inv = 1.0f / s;
#pragma unroll
  for (int j = 0; j < 8; ++j) x[j] *= inv;
  float4 o0 = {x[0], x[1], x[2], x[3]}, o1 = {x[4], x[5], x[6], x[7]};
  ((float4*)(out + base))[2 * t] = o0;
  ((float4*)(out + base))[2 * t + 1] = o1;
  f16x8 ov;
#pragma unroll
  for (int j = 0; j < 8; ++j) ov[j] = (f16)x[j];
  *(f16x8*)(abf + base + (size_t)t * 8) = ov;
}

// --------------------------------------------- fused LN1 + add + LN2
__global__ __launch_bounds__(256) void k_ln(
    const f16* __restrict__ attb, const float* __restrict__ src,
    const float* __restrict__ w1, const float* __restrict__ b1,
    const float* __restrict__ w2, const float* __restrict__ b2,
    float* __restrict__ out)
{
  const size_t base = (size_t)blockIdx.x * 1024;
  const int t = threadIdx.x, lane = t & 63, w = t >> 6;
  f16x4 a4 = ((const f16x4*)(attb + base))[t];
  float ax = (float)a4[0], ay = (float)a4[1], az = (float)a4[2], aw = (float)a4[3];
  float s = ax + ay + az + aw;
  float s2 = ax * ax + ay * ay + az * az + aw * aw;
#pragma unroll
  for (int off = 1; off < 64; off <<= 1) {
    s += __shfl_xor(s, off);
    s2 += __shfl_xor(s2, off);
  }
  __shared__ float red[16];
  if (lane == 0) { red[w] = s; red[4 + w] = s2; }
  __syncthreads();
  s = red[0] + red[1] + red[2] + red[3];
  s2 = red[4] + red[5] + red[6] + red[7];
  float mu = s * (1.0f / 1024.0f);
  float var = s2 * (1.0f / 1024.0f) - mu * mu;
  float rs = rsqrtf(var + 1e-5f);
  float4 W1 = ((const float4*)w1)[t], B1 = ((const float4*)b1)[t];
  float4 sv = ((const float4*)(src + base))[t];
  float y0 = sv.x + (ax - mu) * rs * W1.x + B1.x;
  float y1 = sv.y + (ay - mu) * rs * W1.y + B1.y;
  float y2 = sv.z + (az - mu) * rs * W1.z + B1.z;
  float y3 = sv.w + (aw - mu) * rs * W1.w + B1.w;
  s = y0 + y1 + y2 + y3;
  s2 = y0 * y0 + y1 * y1 + y2 * y2 + y3 * y3;
#pragma unroll
  for (int off = 1; off < 64; off <<= 1) {
    s += __shfl_xor(s, off);
    s2 += __shfl_xor(s2, off);
  }
  if (lane == 0) { red[8 + w] = s; red[12 + w] = s2; }
  __syncthreads();
  s = red[8] + red[9] + red[10] + red[11];
  s2 = red[12] + red[13] + red[14] + red[15];
  mu = s * (1.0f / 1024.0f);
  var = s2 * (1.0f / 1024.0f) - mu * mu;
  rs = rsqrtf(var + 1e-5f);
  float4 W2 = ((const float4*)w2)[t], B2 = ((const float4*)b2)[t];
  float4 o;
  o.x = (y0 - mu) * rs * W2.x + B2.x;
  o.y = (y1 - mu) * rs * W2.y + B2.y;
  o.z = (y2 - mu) * rs * W2.z + B2.z;
  o.w = (y3 - mu) * rs * W2.w + B2.w;
  ((float4*)(out + base))[t] = o;
}

// ---------------------------------------------------------------- launch
extern "C" void kernel_launch(void* const* d_in, const int* in_sizes, int n_in,
                              void* d_out, int out_size, void* d_ws, size_t ws_size,
                              hipStream_t stream) {
  const float* src = (const float*)d_in[0];
  const float* Wq  = (const float*)d_in[1];
  const float* Wk  = (const float*)d_in[2];
  const float* Wv  = (const float*)d_in[3];
  const float* l1w = (const float*)d_in[4];
  const float* l1b = (const float*)d_in[5];
  const float* l2w = (const float*)d_in[6];
  const float* l2b = (const float*)d_in[7];
  float* Xout = (float*)d_out;
  float* Aout = Xout + (size_t)NROWS * D_MODEL;

  // workspace layout (134 MB, non-overlapping)
  char* ws = (char*)d_ws;
  f16* srch = (f16*)ws;                       // 16 MB (8192x1024)
  f16* wt   = (f16*)(ws + (16u << 20));       //  6 MB (3072x1024, W^T)
  f16* qp   = (f16*)(ws + (22u << 20));       // 16 MB
  f16* kp   = (f16*)(ws + (38u << 20));       // 16 MB
  f16* vp   = (f16*)(ws + (54u << 20));       // 16 MB
  f16* vtT  = (f16*)(ws + (70u << 20));       // 16 MB (B,D,S scrambled-T)
  f16* abf  = (f16*)(ws + (86u << 20));       // 32 MB (B,S,S scores->a f16)
  f16* attb = (f16*)(ws + (118u << 20));      // 16 MB (B,S,D f16)

  k_cast_f16<<<4096, 256, 0, stream>>>(src, srch);
  k_castT<<<dim3(16, 16, 3), 256, 0, stream>>>(Wq, Wk, Wv, wt);
  k_qkv3<<<dim3(32, 24), 512, 0, stream>>>(srch, wt, qp, kp, vp);
  k_scrT<<<dim3(32, 16, 4), 256, 0, stream>>>(vp, vtT);
  k_scores<<<dim3(8, 8, 4), 512, 0, stream>>>(qp, kp, abf);
  k_softmax<<<NROWS, 256, 0, stream>>>(Aout, abf);
  k_att<<<dim3(8, 8, 4), 512, 0, stream>>>(abf, vtT, attb);
  k_ln<<<NROWS, 256, 0, stream>>>(attb, src, l1w, l1b, l2w, l2b, Xout);
}